// Round 3
// baseline (943.722 us; speedup 1.0000x reference)
//
#include <hip/hip_runtime.h>
#include <math.h>

#define N_NODES 100000
#define N_EDGES 800000
#define NBLK 391  // ceil(N_NODES/256)

// ----------------------------------------------------------- CSR construction
__global__ void k_count(const int* __restrict__ col, int* __restrict__ cnt) {
    int e = blockIdx.x * 256 + threadIdx.x;
    if (e < N_EDGES) {
        unsigned c = (unsigned)col[e];
        if (c < N_NODES) atomicAdd(&cnt[c], 1);
    }
}

__global__ void k_blocksum(const int* __restrict__ cnt, int* __restrict__ bsum) {
    __shared__ int sc[256];
    int t = threadIdx.x, i = blockIdx.x * 256 + t;
    sc[t] = (i < N_NODES) ? cnt[i] : 0;
    __syncthreads();
    for (int o = 128; o; o >>= 1) {
        if (t < o) sc[t] += sc[t + o];
        __syncthreads();
    }
    if (t == 0) bsum[blockIdx.x] = sc[0];
}

// one-block parallel scan over the 391 block sums (replaces serial 1-thread loop)
__global__ void k_scanblocks(const int* __restrict__ bsum, int* __restrict__ bexcl) {
    __shared__ int s[512];
    int t = threadIdx.x;
    s[t] = (t < NBLK) ? bsum[t] : 0;
    __syncthreads();
    for (int o = 1; o < 512; o <<= 1) {
        int v = (t >= o) ? s[t - o] : 0;
        __syncthreads();
        s[t] += v;
        __syncthreads();
    }
    if (t < NBLK) bexcl[t] = t ? s[t - 1] : 0;
}

__global__ void k_offsets(const int* __restrict__ cnt, const int* __restrict__ bexcl,
                          int* __restrict__ off, int* __restrict__ pos,
                          int2* __restrict__ offcnt) {
    __shared__ int sc[256];
    int t = threadIdx.x, i = blockIdx.x * 256 + t;
    int v = (i < N_NODES) ? cnt[i] : 0;
    sc[t] = v;
    __syncthreads();
    for (int o = 1; o < 256; o <<= 1) {
        int tv = (t >= o) ? sc[t - o] : 0;
        __syncthreads();
        sc[t] += tv;
        __syncthreads();
    }
    if (i < N_NODES) {
        int s = bexcl[blockIdx.x] + (sc[t] - v);
        off[i] = s;
        pos[i] = s;
        if (offcnt) offcnt[i] = make_int2(s, v);
    }
}

__global__ void k_dinv(const int* __restrict__ cnt, float* __restrict__ dinv) {
    int i = blockIdx.x * 256 + threadIdx.x;
    if (i < N_NODES) dinv[i] = rsqrtf((float)(cnt[i] + 1)); // +1 self-loop
}

// builds CSR; also precomputes dinvE[slot] = dinv[src] to kill one gather indirection
__global__ void k_build(const int* __restrict__ row, const int* __restrict__ col,
                        int* __restrict__ pos, const float* __restrict__ dinv,
                        int* __restrict__ srcE, int* __restrict__ eidE,
                        float* __restrict__ dinvE) {
    int e = blockIdx.x * 256 + threadIdx.x;
    if (e < N_EDGES) {
        unsigned r = (unsigned)row[e], c = (unsigned)col[e];
        if (r < N_NODES && c < N_NODES) {
            int slot = atomicAdd(&pos[c], 1);
            srcE[slot] = (int)r;
            eidE[slot] = e;
            if (dinvE) dinvE[slot] = dinv[r];
        }
    }
}

// -------------------------------------------------- latency-optimized gather
// One wave per destination node. Flat-16 path: ALL metadata via bulk scalar
// loads (arrays padded +16 entries; lanes beyond d neutralized by v=0 +
// index clamp), then ALL 16 X-loads (+16 EA-loads in mode 0) issued before
// any wait -> one VMEM latency instead of ~2.5 chained rounds.
// Writes the finished activation row:
//   act[c][0:128]   = dinv[c]*aggX + dinv[c]^2 * X[c]
//   act[c][128:192] = dinv[c]*aggEA   (mode 0 only; layer-invariant)
template<int MODE>
__global__ __launch_bounds__(256) void k_gather(
    const float* __restrict__ X, const float* __restrict__ EAraw,
    const int2* __restrict__ offcnt,
    const int* __restrict__ srcE, const int* __restrict__ eidE,
    const float* __restrict__ dinvE, const float* __restrict__ dinv,
    float* __restrict__ act)
{
    int w = threadIdx.x >> 6, l = threadIdx.x & 63;
    int c = blockIdx.x * 4 + w;
    if (c >= N_NODES) return;
    int2 oc = offcnt[c];
    int beg = oc.x, d = oc.y;
    const float2* X2 = (const float2*)X;

    // ---- bulk wave-uniform metadata loads (contiguous -> s_load_dwordx8)
    int sU[16]; float vU[16]; int eU[16];
    #pragma unroll
    for (int i = 0; i < 16; i++) sU[i] = srcE[beg + i];
    #pragma unroll
    for (int i = 0; i < 16; i++) vU[i] = dinvE[beg + i];
    if (MODE == 0) {
        #pragma unroll
        for (int i = 0; i < 16; i++) eU[i] = eidE[beg + i];
    }
    #pragma unroll
    for (int i = 0; i < 16; i++) {
        if (i >= d) vU[i] = 0.f;                                   // neutralize pad
        sU[i] = ((unsigned)sU[i] < N_NODES) ? sU[i] : 0;           // clamp garbage
        if (MODE == 0) eU[i] = ((unsigned)eU[i] < N_EDGES) ? eU[i] : 0;
    }

    // ---- issue all gathers before any accumulation
    float2 xv[16];
    #pragma unroll
    for (int i = 0; i < 16; i++) xv[i] = X2[(size_t)sU[i] * 64 + l];
    float ev[16];
    if (MODE == 0) {
        #pragma unroll
        for (int i = 0; i < 16; i++) ev[i] = EAraw[(size_t)eU[i] * 64 + l];
    }

    float a0 = 0.f, a1 = 0.f, ae = 0.f;
    float b0 = 0.f, b1 = 0.f, be = 0.f;
    #pragma unroll
    for (int i = 0; i < 16; i += 2) {
        a0 += vU[i] * xv[i].x;
        a1 += vU[i] * xv[i].y;
        b0 += vU[i + 1] * xv[i + 1].x;
        b1 += vU[i + 1] * xv[i + 1].y;
        if (MODE == 0) {
            ae += vU[i] * ev[i];
            be += vU[i + 1] * ev[i + 1];
        }
    }
    a0 += b0; a1 += b1; ae += be;

    // ---- rare tail (P(d>16) ~ 0.4% for Poisson(8))
    for (int j = 16; j < d; j++) {
        int s = srcE[beg + j];
        float v = dinvE[beg + j];
        float2 x = X2[(size_t)s * 64 + l];
        a0 += v * x.x;
        a1 += v * x.y;
        if (MODE == 0) ae += v * EAraw[(size_t)eidE[beg + j] * 64 + l];
    }

    float dv = dinv[c], dv2 = dv * dv;
    float2 xc = X2[(size_t)c * 64 + l];
    float* arow = act + (size_t)c * 192;
    ((float2*)arow)[l] = make_float2(dv * a0 + dv2 * xc.x, dv * a1 + dv2 * xc.y);
    if (MODE == 0) arow[128 + l] = dv * ae;
}

// -------------------------------------------------- LDS-broadcast GEMM
// out[c] = gelu( act[c][0:192] @ [Wn;We] + bias )
// Block = 4 waves = 64 rows. Stage act rows (48 KB, contiguous) into LDS with
// coalesced float4 loads; each wave owns 16 rows x 128 cols, act read via
// wave-uniform ds_read_b128 broadcast. 32 FMAs per lane per weight float2.
__global__ __launch_bounds__(256, 3) void k_gemm(
    const float* __restrict__ act,
    const float* __restrict__ Wn, const float* __restrict__ We,
    const float* __restrict__ bias, float* __restrict__ out)
{
    __shared__ float sact[64][192];
    int t = threadIdx.x;
    int w = t >> 6, l = t & 63;

    const size_t CAP = (size_t)N_NODES * 192;
    size_t base = (size_t)blockIdx.x * (64 * 192);
    #pragma unroll
    for (int i = 0; i < 12; i++) {
        size_t fi = base + (size_t)(i * 256 + t) * 4;
        float4 v = make_float4(0.f, 0.f, 0.f, 0.f);
        if (fi + 4 <= CAP) v = *(const float4*)(act + fi);
        *(float4*)&sact[0][(i * 256 + t) * 4] = v;
    }
    __syncthreads();

    int row0 = blockIdx.x * 64 + w * 16;
    float acc[16][2] = {};

    const float2* Wn2 = (const float2*)Wn;
    for (int k = 0; k < 128; k += 4) {
        float2 w0 = Wn2[(k + 0) * 64 + l];
        float2 w1 = Wn2[(k + 1) * 64 + l];
        float2 w2 = Wn2[(k + 2) * 64 + l];
        float2 w3 = Wn2[(k + 3) * 64 + l];
        #pragma unroll
        for (int r = 0; r < 16; r++) {
            float4 a = *(const float4*)&sact[w * 16 + r][k];
            acc[r][0] += a.x * w0.x + a.y * w1.x + a.z * w2.x + a.w * w3.x;
            acc[r][1] += a.x * w0.y + a.y * w1.y + a.z * w2.y + a.w * w3.y;
        }
    }

    const float2* We2 = (const float2*)We;
    for (int k = 0; k < 64; k += 4) {
        float2 w0 = We2[(k + 0) * 64 + l];
        float2 w1 = We2[(k + 1) * 64 + l];
        float2 w2 = We2[(k + 2) * 64 + l];
        float2 w3 = We2[(k + 3) * 64 + l];
        #pragma unroll
        for (int r = 0; r < 16; r++) {
            float4 a = *(const float4*)&sact[w * 16 + r][128 + k];
            acc[r][0] += a.x * w0.x + a.y * w1.x + a.z * w2.x + a.w * w3.x;
            acc[r][1] += a.x * w0.y + a.y * w1.y + a.z * w2.y + a.w * w3.y;
        }
    }

    float2 bb = ((const float2*)bias)[l];
    #pragma unroll
    for (int r = 0; r < 16; r++) {
        int c = row0 + r;
        if (c >= N_NODES) break;
        float v0 = acc[r][0] + bb.x;
        float v1 = acc[r][1] + bb.y;
        v0 = 0.5f * v0 * (1.0f + erff(v0 * 0.70710678f)); // exact gelu
        v1 = 0.5f * v1 * (1.0f + erff(v1 * 0.70710678f));
        ((float2*)out)[(size_t)c * 64 + l] = make_float2(v0, v1);
    }
}

// --------------------- fused fallback (round-3 proven path, small workspace)
__global__ __launch_bounds__(256) void k_layer(
    const float* __restrict__ X, const float* __restrict__ EAraw,
    const float* __restrict__ EaIn, float* __restrict__ EaOut,
    const int* __restrict__ off, const int* __restrict__ cnt,
    const int* __restrict__ srcE, const int* __restrict__ eidE,
    const float* __restrict__ dinv,
    const float* __restrict__ Wn, const float* __restrict__ We,
    const float* __restrict__ bias, float* __restrict__ out, int mode)
{
    __shared__ float act[4][4][192];
    int w = threadIdx.x >> 6, l = threadIdx.x & 63;
    int row0 = blockIdx.x * 16 + w * 4;

    for (int r = 0; r < 4; r++) {
        int c = row0 + r;
        int beg = off[c];
        int d = cnt[c];
        float a0 = 0.f, a1 = 0.f, ae = 0.f;
        for (int j = 0; j < d; j++) {
            unsigned s = (unsigned)srcE[beg + j];
            if (s >= N_NODES) continue;
            float sv = dinv[s];
            float2 xv = ((const float2*)X)[s * 64 + l];
            a0 += sv * xv.x;
            a1 += sv * xv.y;
            if (mode == 0) {
                unsigned e = (unsigned)eidE[beg + j];
                if (e < N_EDGES) ae += sv * EAraw[e * 64 + l];
            }
        }
        float dv = dinv[c], dv2 = dv * dv;
        float2 xc = ((const float2*)X)[c * 64 + l];
        act[w][r][2 * l]     = dv * a0 + dv2 * xc.x;
        act[w][r][2 * l + 1] = dv * a1 + dv2 * xc.y;
        if (mode == 0) {
            act[w][r][128 + l] = dv * ae;
            EaOut[c * 64 + l] = ae;
        } else {
            act[w][r][128 + l] = dv * EaIn[c * 64 + l];
        }
    }
    __syncthreads();

    float acc[4][2] = {};
    for (int k = 0; k < 128; k++) {
        float2 wv = ((const float2*)Wn)[k * 64 + l];
        #pragma unroll
        for (int r = 0; r < 4; r++) {
            float a = act[w][r][k];
            acc[r][0] += a * wv.x;
            acc[r][1] += a * wv.y;
        }
    }
    for (int k = 0; k < 64; k++) {
        float2 wv = ((const float2*)We)[k * 64 + l];
        #pragma unroll
        for (int r = 0; r < 4; r++) {
            float a = act[w][r][128 + k];
            acc[r][0] += a * wv.x;
            acc[r][1] += a * wv.y;
        }
    }

    float2 bb = ((const float2*)bias)[l];
    for (int r = 0; r < 4; r++) {
        float v0 = acc[r][0] + bb.x;
        float v1 = acc[r][1] + bb.y;
        v0 = 0.5f * v0 * (1.0f + erff(v0 * 0.70710678f));
        v1 = 0.5f * v1 * (1.0f + erff(v1 * 0.70710678f));
        ((float2*)out)[(row0 + r) * 64 + l] = make_float2(v0, v1);
    }
}

// ------------------------------------ final: h2 @ W_out + b_out + x, LayerNorm
__global__ __launch_bounds__(256) void k_final(
    const float* __restrict__ h2, const float* __restrict__ x,
    const float* __restrict__ Wo, const float* __restrict__ bo,
    const float* __restrict__ g, const float* __restrict__ lb,
    float* __restrict__ out)
{
    __shared__ float lds[4][4][128];
    int w = threadIdx.x >> 6, l = threadIdx.x & 63;
    int row0 = blockIdx.x * 16 + w * 4;

    for (int r = 0; r < 4; r++) {
        int c = row0 + r;
        float2 hv = ((const float2*)h2)[(size_t)c * 64 + l];
        lds[w][r][2 * l]     = hv.x;
        lds[w][r][2 * l + 1] = hv.y;
    }
    __syncthreads();

    float acc[4][2] = {};
    const float2* Wo2 = (const float2*)Wo;
    for (int k = 0; k < 128; k += 4) {
        float2 w0 = Wo2[(k + 0) * 64 + l];
        float2 w1 = Wo2[(k + 1) * 64 + l];
        float2 w2 = Wo2[(k + 2) * 64 + l];
        float2 w3 = Wo2[(k + 3) * 64 + l];
        #pragma unroll
        for (int r = 0; r < 4; r++) {
            float4 a = *(const float4*)&lds[w][r][k];
            acc[r][0] += a.x * w0.x + a.y * w1.x + a.z * w2.x + a.w * w3.x;
            acc[r][1] += a.x * w0.y + a.y * w1.y + a.z * w2.y + a.w * w3.y;
        }
    }

    float2 bov = ((const float2*)bo)[l];
    float2 gv  = ((const float2*)g)[l];
    float2 lbv = ((const float2*)lb)[l];

    for (int r = 0; r < 4; r++) {
        int c = row0 + r;
        float2 xv = ((const float2*)x)[(size_t)c * 64 + l];
        float v0 = acc[r][0] + bov.x + xv.x;
        float v1 = acc[r][1] + bov.y + xv.y;
        float s = v0 + v1;
        #pragma unroll
        for (int o = 32; o; o >>= 1) s += __shfl_xor(s, o, 64);
        float mu = s * (1.0f / 128.0f);
        float d0 = v0 - mu, d1 = v1 - mu;
        float sq = d0 * d0 + d1 * d1;
        #pragma unroll
        for (int o = 32; o; o >>= 1) sq += __shfl_xor(sq, o, 64);
        float rs = rsqrtf(sq * (1.0f / 128.0f) + 1e-5f);
        float2 ov;
        ov.x = d0 * rs * gv.x + lbv.x;
        ov.y = d1 * rs * gv.y + lbv.y;
        ((float2*)out)[(size_t)c * 64 + l] = ov;
    }
}

extern "C" void kernel_launch(void* const* d_in, const int* in_sizes, int n_in,
                              void* d_out, int out_size, void* d_ws, size_t ws_size,
                              hipStream_t stream)
{
    const float* x   = (const float*)d_in[0];
    const int*   ei  = (const int*)d_in[1];
    const float* ea  = (const float*)d_in[2];
    // d_in[3..6] (W_qkv, b_qkv, W_ek, b_ek) are dead code in the reference.
    const float* Wn1 = (const float*)d_in[7];
    const float* We1 = (const float*)d_in[8];
    const float* b1  = (const float*)d_in[9];
    const float* Wn2 = (const float*)d_in[10];
    const float* We2 = (const float*)d_in[11];
    const float* b2  = (const float*)d_in[12];
    const float* Wo  = (const float*)d_in[13];
    const float* bo  = (const float*)d_in[14];
    const float* lng = (const float*)d_in[15];
    const float* lnb = (const float*)d_in[16];
    const int* row = ei;
    const int* col = ei + N_EDGES;

    char* ws = (char*)d_ws;
    size_t off_b = 0;
    auto alloc = [&](size_t bytes) {
        void* p = ws + off_b;
        off_b += (bytes + 255) & ~(size_t)255;
        return p;
    };
    // ---- common workspace (~60 MB): CSR + h1  (edge arrays padded +16 entries
    //      so the gather's flat-16 bulk loads never run off the end)
    int*   cnt   = (int*)  alloc((size_t)N_NODES * 4);
    int*   off   = (int*)  alloc((size_t)N_NODES * 4);
    int*   pos   = (int*)  alloc((size_t)N_NODES * 4);
    int*   bsum  = (int*)  alloc((size_t)NBLK * 4);
    int*   bexcl = (int*)  alloc((size_t)NBLK * 4);
    float* dinv  = (float*)alloc((size_t)N_NODES * 4);
    int*   srcE  = (int*)  alloc((size_t)(N_EDGES + 16) * 4);
    int*   eidE  = (int*)  alloc((size_t)(N_EDGES + 16) * 4);
    float* h1    = (float*)alloc((size_t)N_NODES * 128 * 4);
    size_t common_end = off_b;

    // ---- split-path extras: dinvE + offcnt + act[N][192]
    float* dinvE  = (float*)alloc((size_t)(N_EDGES + 16) * 4);
    int2*  offcnt = (int2*) alloc((size_t)N_NODES * 8);
    float* act    = (float*)alloc((size_t)N_NODES * 192 * 4);
    size_t split_end = off_b;

    // ---- fused-path extras overlap the split-path region (paths exclusive)
    float* Ea = (float*)(ws + common_end);
    size_t fused_end = common_end + (((size_t)N_NODES * 64 * 4 + 255) & ~(size_t)255);

    bool use_split = (split_end <= ws_size);
    if (!use_split && fused_end > ws_size) return; // finite-wrong signature, diagnosable

    float* h2 = (float*)d_out;    // staged in d_out; k_final runs in place

    hipMemsetAsync(cnt, 0, (size_t)N_NODES * 4, stream);

    k_count     <<<(N_EDGES + 255) / 256, 256, 0, stream>>>(col, cnt);
    k_blocksum  <<<NBLK, 256, 0, stream>>>(cnt, bsum);
    k_scanblocks<<<1, 512, 0, stream>>>(bsum, bexcl);
    k_offsets   <<<NBLK, 256, 0, stream>>>(cnt, bexcl, off, pos,
                                           use_split ? offcnt : nullptr);
    k_dinv      <<<NBLK, 256, 0, stream>>>(cnt, dinv);
    k_build     <<<(N_EDGES + 255) / 256, 256, 0, stream>>>(
        row, col, pos, dinv, srcE, eidE, use_split ? dinvE : nullptr);

    if (use_split) {
        k_gather<0><<<(N_NODES + 3) / 4, 256, 0, stream>>>(x, ea, offcnt,
                                                           srcE, eidE, dinvE, dinv, act);
        k_gemm  <<<(N_NODES + 63) / 64, 256, 0, stream>>>(act, Wn1, We1, b1, h1);
        k_gather<1><<<(N_NODES + 3) / 4, 256, 0, stream>>>(h1, nullptr, offcnt,
                                                           srcE, eidE, dinvE, dinv, act);
        k_gemm  <<<(N_NODES + 63) / 64, 256, 0, stream>>>(act, Wn2, We2, b2, h2);
    } else {
        k_layer<<<N_NODES / 16, 256, 0, stream>>>(x, ea, nullptr, Ea,
                                                  off, cnt, srcE, eidE, dinv,
                                                  Wn1, We1, b1, h1, 0);
        k_layer<<<N_NODES / 16, 256, 0, stream>>>(h1, nullptr, Ea, nullptr,
                                                  off, cnt, srcE, eidE, dinv,
                                                  Wn2, We2, b2, h2, 1);
    }
    k_final<<<N_NODES / 16, 256, 0, stream>>>(h2, x, Wo, bo, lng, lnb, (float*)d_out);
}

// Round 4
// 879.635 us; speedup vs baseline: 1.0729x; 1.0729x over previous
//
#include <hip/hip_runtime.h>
#include <math.h>

#define N_NODES 100000
#define N_EDGES 800000
#define NBLK 391  // ceil(N_NODES/256)

// ----------------------------------------------------------- CSR construction
__global__ void k_count(const int* __restrict__ col, int* __restrict__ cnt) {
    int e = blockIdx.x * 256 + threadIdx.x;
    if (e < N_EDGES) {
        unsigned c = (unsigned)col[e];
        if (c < N_NODES) atomicAdd(&cnt[c], 1);
    }
}

__global__ void k_blocksum(const int* __restrict__ cnt, int* __restrict__ bsum) {
    __shared__ int sc[256];
    int t = threadIdx.x, i = blockIdx.x * 256 + t;
    sc[t] = (i < N_NODES) ? cnt[i] : 0;
    __syncthreads();
    for (int o = 128; o; o >>= 1) {
        if (t < o) sc[t] += sc[t + o];
        __syncthreads();
    }
    if (t == 0) bsum[blockIdx.x] = sc[0];
}

// one-block parallel scan over the 391 block sums
__global__ void k_scanblocks(const int* __restrict__ bsum, int* __restrict__ bexcl) {
    __shared__ int s[512];
    int t = threadIdx.x;
    s[t] = (t < NBLK) ? bsum[t] : 0;
    __syncthreads();
    for (int o = 1; o < 512; o <<= 1) {
        int v = (t >= o) ? s[t - o] : 0;
        __syncthreads();
        s[t] += v;
        __syncthreads();
    }
    if (t < NBLK) bexcl[t] = t ? s[t - 1] : 0;
}

__global__ void k_offsets(const int* __restrict__ cnt, const int* __restrict__ bexcl,
                          int* __restrict__ off, int* __restrict__ pos,
                          int2* __restrict__ offcnt) {
    __shared__ int sc[256];
    int t = threadIdx.x, i = blockIdx.x * 256 + t;
    int v = (i < N_NODES) ? cnt[i] : 0;
    sc[t] = v;
    __syncthreads();
    for (int o = 1; o < 256; o <<= 1) {
        int tv = (t >= o) ? sc[t - o] : 0;
        __syncthreads();
        sc[t] += tv;
        __syncthreads();
    }
    if (i < N_NODES) {
        int s = bexcl[blockIdx.x] + (sc[t] - v);
        off[i] = s;
        pos[i] = s;
        if (offcnt) offcnt[i] = make_int2(s, v);
    }
}

__global__ void k_dinv(const int* __restrict__ cnt, float* __restrict__ dinv) {
    int i = blockIdx.x * 256 + threadIdx.x;
    if (i < N_NODES) dinv[i] = rsqrtf((float)(cnt[i] + 1)); // +1 self-loop
}

// builds CSR; also precomputes dinvE[slot] = dinv[src] to kill one gather indirection
__global__ void k_build(const int* __restrict__ row, const int* __restrict__ col,
                        int* __restrict__ pos, const float* __restrict__ dinv,
                        int* __restrict__ srcE, int* __restrict__ eidE,
                        float* __restrict__ dinvE) {
    int e = blockIdx.x * 256 + threadIdx.x;
    if (e < N_EDGES) {
        unsigned r = (unsigned)row[e], c = (unsigned)col[e];
        if (r < N_NODES && c < N_NODES) {
            int slot = atomicAdd(&pos[c], 1);
            srcE[slot] = (int)r;
            eidE[slot] = e;
            if (dinvE) dinvE[slot] = dinv[r];
        }
    }
}

// -------------------------------------------------- latency-optimized gather
// One wave per destination node. Flat-16: bulk scalar metadata loads, then all
// vector gathers issued in one round. Pad lanes (i >= d, wave-uniform compare)
// get v=0 and are REDIRECTED to entry 0's row (already being fetched by lane 0
// -> L1 hit, zero extra HBM traffic). Round-3's bug was clamping by value
// range instead: pads dereferenced OTHER nodes' valid indices (+92 MB fetch).
// Writes the finished activation row:
//   act[c][0:128]   = dinv[c]*aggX + dinv[c]^2 * X[c]
//   act[c][128:192] = dinv[c]*aggEA   (mode 0 only; layer-invariant)
template<int MODE>
__global__ __launch_bounds__(256) void k_gather(
    const float* __restrict__ X, const float* __restrict__ EAraw,
    const int2* __restrict__ offcnt,
    const int* __restrict__ srcE, const int* __restrict__ eidE,
    const float* __restrict__ dinvE, const float* __restrict__ dinv,
    float* __restrict__ act)
{
    int w = threadIdx.x >> 6, l = threadIdx.x & 63;
    int c = blockIdx.x * 4 + w;
    if (c >= N_NODES) return;
    int2 oc = offcnt[c];
    int beg = __builtin_amdgcn_readfirstlane(oc.x);
    int d   = __builtin_amdgcn_readfirstlane(oc.y);
    const float2* X2 = (const float2*)X;

    float2 xc = X2[(size_t)c * 64 + l];   // self row: issue early, overlaps gathers
    float dv = dinv[c];

    // ---- bulk wave-uniform metadata loads (contiguous -> s_load_dwordx8)
    int sU[16]; float vU[16]; int eU[16];
    #pragma unroll
    for (int i = 0; i < 16; i++) sU[i] = srcE[beg + i];
    #pragma unroll
    for (int i = 0; i < 16; i++) vU[i] = dinvE[beg + i];
    if (MODE == 0) {
        #pragma unroll
        for (int i = 0; i < 16; i++) eU[i] = eidE[beg + i];
    }
    int s0 = (d > 0) ? sU[0] : 0;      // d==0 -> index 0 (valid row, v=0 anyway)
    int e0 = (d > 0) ? eU[0] : 0;
    #pragma unroll
    for (int i = 0; i < 16; i++) {
        if (i >= d) {                   // wave-uniform scalar select per i
            vU[i] = 0.f;
            sU[i] = s0;
            if (MODE == 0) eU[i] = e0;
        }
    }

    // ---- issue all gathers before any accumulation
    float2 xv[16];
    #pragma unroll
    for (int i = 0; i < 16; i++) xv[i] = X2[(size_t)sU[i] * 64 + l];
    float evv[16];
    if (MODE == 0) {
        #pragma unroll
        for (int i = 0; i < 16; i++) evv[i] = EAraw[(size_t)eU[i] * 64 + l];
    }

    // sequential accumulation (round-2 summation order; keeps absmax low)
    float a0 = 0.f, a1 = 0.f, ae = 0.f;
    #pragma unroll
    for (int i = 0; i < 16; i++) {
        a0 += vU[i] * xv[i].x;
        a1 += vU[i] * xv[i].y;
        if (MODE == 0) ae += vU[i] * evv[i];
    }

    // ---- rare tail (P(d>16) ~ 0.4% for Poisson(8))
    for (int j = 16; j < d; j++) {
        int s = srcE[beg + j];
        float v = dinvE[beg + j];
        float2 x = X2[(size_t)s * 64 + l];
        a0 += v * x.x;
        a1 += v * x.y;
        if (MODE == 0) ae += v * EAraw[(size_t)eidE[beg + j] * 64 + l];
    }

    float dv2 = dv * dv;
    float* arow = act + (size_t)c * 192;
    ((float2*)arow)[l] = make_float2(dv * a0 + dv2 * xc.x, dv * a1 + dv2 * xc.y);
    if (MODE == 0) arow[128 + l] = dv * ae;
}

// -------------------------------------------------- LDS-broadcast GEMM
// out[c] = gelu( act[c][0:192] @ [Wn;We] + bias )
// Block = 4 waves = 64 rows. Stage act rows (48 KB, contiguous) into LDS with
// coalesced float4 loads; each wave owns 16 rows x 128 cols, act read via
// wave-uniform ds_read_b128 broadcast. 32 FMAs per lane per weight float2.
__global__ __launch_bounds__(256, 3) void k_gemm(
    const float* __restrict__ act,
    const float* __restrict__ Wn, const float* __restrict__ We,
    const float* __restrict__ bias, float* __restrict__ out)
{
    __shared__ float sact[64][192];
    int t = threadIdx.x;
    int w = t >> 6, l = t & 63;

    const size_t CAP = (size_t)N_NODES * 192;
    size_t base = (size_t)blockIdx.x * (64 * 192);
    #pragma unroll
    for (int i = 0; i < 12; i++) {
        size_t fi = base + (size_t)(i * 256 + t) * 4;
        float4 v = make_float4(0.f, 0.f, 0.f, 0.f);
        if (fi + 4 <= CAP) v = *(const float4*)(act + fi);
        *(float4*)&sact[0][(i * 256 + t) * 4] = v;
    }
    __syncthreads();

    int row0 = blockIdx.x * 64 + w * 16;
    float acc[16][2] = {};

    const float2* Wn2 = (const float2*)Wn;
    for (int k = 0; k < 128; k += 4) {
        float2 w0 = Wn2[(k + 0) * 64 + l];
        float2 w1 = Wn2[(k + 1) * 64 + l];
        float2 w2 = Wn2[(k + 2) * 64 + l];
        float2 w3 = Wn2[(k + 3) * 64 + l];
        #pragma unroll
        for (int r = 0; r < 16; r++) {
            float4 a = *(const float4*)&sact[w * 16 + r][k];
            acc[r][0] += a.x * w0.x + a.y * w1.x + a.z * w2.x + a.w * w3.x;
            acc[r][1] += a.x * w0.y + a.y * w1.y + a.z * w2.y + a.w * w3.y;
        }
    }

    const float2* We2 = (const float2*)We;
    for (int k = 0; k < 64; k += 4) {
        float2 w0 = We2[(k + 0) * 64 + l];
        float2 w1 = We2[(k + 1) * 64 + l];
        float2 w2 = We2[(k + 2) * 64 + l];
        float2 w3 = We2[(k + 3) * 64 + l];
        #pragma unroll
        for (int r = 0; r < 16; r++) {
            float4 a = *(const float4*)&sact[w * 16 + r][128 + k];
            acc[r][0] += a.x * w0.x + a.y * w1.x + a.z * w2.x + a.w * w3.x;
            acc[r][1] += a.x * w0.y + a.y * w1.y + a.z * w2.y + a.w * w3.y;
        }
    }

    float2 bb = ((const float2*)bias)[l];
    #pragma unroll
    for (int r = 0; r < 16; r++) {
        int c = row0 + r;
        if (c >= N_NODES) break;
        float v0 = acc[r][0] + bb.x;
        float v1 = acc[r][1] + bb.y;
        v0 = 0.5f * v0 * (1.0f + erff(v0 * 0.70710678f)); // exact gelu
        v1 = 0.5f * v1 * (1.0f + erff(v1 * 0.70710678f));
        ((float2*)out)[(size_t)c * 64 + l] = make_float2(v0, v1);
    }
}

// --------------------- fused fallback (proven path, small workspace)
__global__ __launch_bounds__(256) void k_layer(
    const float* __restrict__ X, const float* __restrict__ EAraw,
    const float* __restrict__ EaIn, float* __restrict__ EaOut,
    const int* __restrict__ off, const int* __restrict__ cnt,
    const int* __restrict__ srcE, const int* __restrict__ eidE,
    const float* __restrict__ dinv,
    const float* __restrict__ Wn, const float* __restrict__ We,
    const float* __restrict__ bias, float* __restrict__ out, int mode)
{
    __shared__ float act[4][4][192];
    int w = threadIdx.x >> 6, l = threadIdx.x & 63;
    int row0 = blockIdx.x * 16 + w * 4;

    for (int r = 0; r < 4; r++) {
        int c = row0 + r;
        int beg = off[c];
        int d = cnt[c];
        float a0 = 0.f, a1 = 0.f, ae = 0.f;
        for (int j = 0; j < d; j++) {
            unsigned s = (unsigned)srcE[beg + j];
            if (s >= N_NODES) continue;
            float sv = dinv[s];
            float2 xv = ((const float2*)X)[s * 64 + l];
            a0 += sv * xv.x;
            a1 += sv * xv.y;
            if (mode == 0) {
                unsigned e = (unsigned)eidE[beg + j];
                if (e < N_EDGES) ae += sv * EAraw[e * 64 + l];
            }
        }
        float dv = dinv[c], dv2 = dv * dv;
        float2 xc = ((const float2*)X)[c * 64 + l];
        act[w][r][2 * l]     = dv * a0 + dv2 * xc.x;
        act[w][r][2 * l + 1] = dv * a1 + dv2 * xc.y;
        if (mode == 0) {
            act[w][r][128 + l] = dv * ae;
            EaOut[c * 64 + l] = ae;
        } else {
            act[w][r][128 + l] = dv * EaIn[c * 64 + l];
        }
    }
    __syncthreads();

    float acc[4][2] = {};
    for (int k = 0; k < 128; k++) {
        float2 wv = ((const float2*)Wn)[k * 64 + l];
        #pragma unroll
        for (int r = 0; r < 4; r++) {
            float a = act[w][r][k];
            acc[r][0] += a * wv.x;
            acc[r][1] += a * wv.y;
        }
    }
    for (int k = 0; k < 64; k++) {
        float2 wv = ((const float2*)We)[k * 64 + l];
        #pragma unroll
        for (int r = 0; r < 4; r++) {
            float a = act[w][r][128 + k];
            acc[r][0] += a * wv.x;
            acc[r][1] += a * wv.y;
        }
    }

    float2 bb = ((const float2*)bias)[l];
    for (int r = 0; r < 4; r++) {
        float v0 = acc[r][0] + bb.x;
        float v1 = acc[r][1] + bb.y;
        v0 = 0.5f * v0 * (1.0f + erff(v0 * 0.70710678f));
        v1 = 0.5f * v1 * (1.0f + erff(v1 * 0.70710678f));
        ((float2*)out)[(row0 + r) * 64 + l] = make_float2(v0, v1);
    }
}

// ------------------------------------ final: h2 @ W_out + b_out + x, LayerNorm
__global__ __launch_bounds__(256) void k_final(
    const float* __restrict__ h2, const float* __restrict__ x,
    const float* __restrict__ Wo, const float* __restrict__ bo,
    const float* __restrict__ g, const float* __restrict__ lb,
    float* __restrict__ out)
{
    __shared__ float lds[4][4][128];
    int w = threadIdx.x >> 6, l = threadIdx.x & 63;
    int row0 = blockIdx.x * 16 + w * 4;

    for (int r = 0; r < 4; r++) {
        int c = row0 + r;
        float2 hv = ((const float2*)h2)[(size_t)c * 64 + l];
        lds[w][r][2 * l]     = hv.x;
        lds[w][r][2 * l + 1] = hv.y;
    }
    __syncthreads();

    float acc[4][2] = {};
    const float2* Wo2 = (const float2*)Wo;
    for (int k = 0; k < 128; k += 4) {
        float2 w0 = Wo2[(k + 0) * 64 + l];
        float2 w1 = Wo2[(k + 1) * 64 + l];
        float2 w2 = Wo2[(k + 2) * 64 + l];
        float2 w3 = Wo2[(k + 3) * 64 + l];
        #pragma unroll
        for (int r = 0; r < 4; r++) {
            float4 a = *(const float4*)&lds[w][r][k];
            acc[r][0] += a.x * w0.x + a.y * w1.x + a.z * w2.x + a.w * w3.x;
            acc[r][1] += a.x * w0.y + a.y * w1.y + a.z * w2.y + a.w * w3.y;
        }
    }

    float2 bov = ((const float2*)bo)[l];
    float2 gv  = ((const float2*)g)[l];
    float2 lbv = ((const float2*)lb)[l];

    for (int r = 0; r < 4; r++) {
        int c = row0 + r;
        float2 xv = ((const float2*)x)[(size_t)c * 64 + l];
        float v0 = acc[r][0] + bov.x + xv.x;
        float v1 = acc[r][1] + bov.y + xv.y;
        float s = v0 + v1;
        #pragma unroll
        for (int o = 32; o; o >>= 1) s += __shfl_xor(s, o, 64);
        float mu = s * (1.0f / 128.0f);
        float d0 = v0 - mu, d1 = v1 - mu;
        float sq = d0 * d0 + d1 * d1;
        #pragma unroll
        for (int o = 32; o; o >>= 1) sq += __shfl_xor(sq, o, 64);
        float rs = rsqrtf(sq * (1.0f / 128.0f) + 1e-5f);
        float2 ov;
        ov.x = d0 * rs * gv.x + lbv.x;
        ov.y = d1 * rs * gv.y + lbv.y;
        ((float2*)out)[(size_t)c * 64 + l] = ov;
    }
}

extern "C" void kernel_launch(void* const* d_in, const int* in_sizes, int n_in,
                              void* d_out, int out_size, void* d_ws, size_t ws_size,
                              hipStream_t stream)
{
    const float* x   = (const float*)d_in[0];
    const int*   ei  = (const int*)d_in[1];
    const float* ea  = (const float*)d_in[2];
    // d_in[3..6] (W_qkv, b_qkv, W_ek, b_ek) are dead code in the reference.
    const float* Wn1 = (const float*)d_in[7];
    const float* We1 = (const float*)d_in[8];
    const float* b1  = (const float*)d_in[9];
    const float* Wn2 = (const float*)d_in[10];
    const float* We2 = (const float*)d_in[11];
    const float* b2  = (const float*)d_in[12];
    const float* Wo  = (const float*)d_in[13];
    const float* bo  = (const float*)d_in[14];
    const float* lng = (const float*)d_in[15];
    const float* lnb = (const float*)d_in[16];
    const int* row = ei;
    const int* col = ei + N_EDGES;

    char* ws = (char*)d_ws;
    size_t off_b = 0;
    auto alloc = [&](size_t bytes) {
        void* p = ws + off_b;
        off_b += (bytes + 255) & ~(size_t)255;
        return p;
    };
    // ---- common workspace: CSR + h1 (edge arrays padded +16 entries so the
    //      gather's flat-16 bulk loads never run off the end)
    int*   cnt   = (int*)  alloc((size_t)N_NODES * 4);
    int*   off   = (int*)  alloc((size_t)N_NODES * 4);
    int*   pos   = (int*)  alloc((size_t)N_NODES * 4);
    int*   bsum  = (int*)  alloc((size_t)NBLK * 4);
    int*   bexcl = (int*)  alloc((size_t)NBLK * 4);
    float* dinv  = (float*)alloc((size_t)N_NODES * 4);
    int*   srcE  = (int*)  alloc((size_t)(N_EDGES + 16) * 4);
    int*   eidE  = (int*)  alloc((size_t)(N_EDGES + 16) * 4);
    float* h1    = (float*)alloc((size_t)N_NODES * 128 * 4);
    size_t common_end = off_b;

    // ---- split-path extras: dinvE + offcnt + act[N][192]
    float* dinvE  = (float*)alloc((size_t)(N_EDGES + 16) * 4);
    int2*  offcnt = (int2*) alloc((size_t)N_NODES * 8);
    float* act    = (float*)alloc((size_t)N_NODES * 192 * 4);
    size_t split_end = off_b;

    // ---- fused-path extras overlap the split-path region (paths exclusive)
    float* Ea = (float*)(ws + common_end);
    size_t fused_end = common_end + (((size_t)N_NODES * 64 * 4 + 255) & ~(size_t)255);

    bool use_split = (split_end <= ws_size);
    if (!use_split && fused_end > ws_size) return; // finite-wrong signature, diagnosable

    float* h2 = (float*)d_out;    // staged in d_out; k_final runs in place

    hipMemsetAsync(cnt, 0, (size_t)N_NODES * 4, stream);

    k_count     <<<(N_EDGES + 255) / 256, 256, 0, stream>>>(col, cnt);
    k_blocksum  <<<NBLK, 256, 0, stream>>>(cnt, bsum);
    k_scanblocks<<<1, 512, 0, stream>>>(bsum, bexcl);
    k_offsets   <<<NBLK, 256, 0, stream>>>(cnt, bexcl, off, pos,
                                           use_split ? offcnt : nullptr);
    k_dinv      <<<NBLK, 256, 0, stream>>>(cnt, dinv);
    k_build     <<<(N_EDGES + 255) / 256, 256, 0, stream>>>(
        row, col, pos, dinv, srcE, eidE, use_split ? dinvE : nullptr);

    if (use_split) {
        k_gather<0><<<(N_NODES + 3) / 4, 256, 0, stream>>>(x, ea, offcnt,
                                                           srcE, eidE, dinvE, dinv, act);
        k_gemm  <<<(N_NODES + 63) / 64, 256, 0, stream>>>(act, Wn1, We1, b1, h1);
        k_gather<1><<<(N_NODES + 3) / 4, 256, 0, stream>>>(h1, nullptr, offcnt,
                                                           srcE, eidE, dinvE, dinv, act);
        k_gemm  <<<(N_NODES + 63) / 64, 256, 0, stream>>>(act, Wn2, We2, b2, h2);
    } else {
        k_layer<<<N_NODES / 16, 256, 0, stream>>>(x, ea, nullptr, Ea,
                                                  off, cnt, srcE, eidE, dinv,
                                                  Wn1, We1, b1, h1, 0);
        k_layer<<<N_NODES / 16, 256, 0, stream>>>(h1, nullptr, Ea, nullptr,
                                                  off, cnt, srcE, eidE, dinv,
                                                  Wn2, We2, b2, h2, 1);
    }
    k_final<<<N_NODES / 16, 256, 0, stream>>>(h2, x, Wo, bo, lng, lnb, (float*)d_out);
}

// Round 5
// 853.429 us; speedup vs baseline: 1.1058x; 1.0307x over previous
//
#include <hip/hip_runtime.h>
#include <math.h>

#define N_NODES 100000
#define N_EDGES 800000
#define NBLK 391  // ceil(N_NODES/256)

// ----------------------------------------------------------- CSR construction
__global__ void k_count(const int* __restrict__ col, int* __restrict__ cnt) {
    int e = blockIdx.x * 256 + threadIdx.x;
    if (e < N_EDGES) {
        unsigned c = (unsigned)col[e];
        if (c < N_NODES) atomicAdd(&cnt[c], 1);
    }
}

__global__ void k_blocksum(const int* __restrict__ cnt, int* __restrict__ bsum) {
    __shared__ int sc[256];
    int t = threadIdx.x, i = blockIdx.x * 256 + t;
    sc[t] = (i < N_NODES) ? cnt[i] : 0;
    __syncthreads();
    for (int o = 128; o; o >>= 1) {
        if (t < o) sc[t] += sc[t + o];
        __syncthreads();
    }
    if (t == 0) bsum[blockIdx.x] = sc[0];
}

// one-block parallel scan over the 391 block sums
__global__ void k_scanblocks(const int* __restrict__ bsum, int* __restrict__ bexcl) {
    __shared__ int s[512];
    int t = threadIdx.x;
    s[t] = (t < NBLK) ? bsum[t] : 0;
    __syncthreads();
    for (int o = 1; o < 512; o <<= 1) {
        int v = (t >= o) ? s[t - o] : 0;
        __syncthreads();
        s[t] += v;
        __syncthreads();
    }
    if (t < NBLK) bexcl[t] = t ? s[t - 1] : 0;
}

// offsets + pos + packed {off,cnt} + dinv (k_dinv folded in: cnt already here)
__global__ void k_offsets(const int* __restrict__ cnt, const int* __restrict__ bexcl,
                          int* __restrict__ off, int* __restrict__ pos,
                          int2* __restrict__ offcnt, float* __restrict__ dinv) {
    __shared__ int sc[256];
    int t = threadIdx.x, i = blockIdx.x * 256 + t;
    int v = (i < N_NODES) ? cnt[i] : 0;
    sc[t] = v;
    __syncthreads();
    for (int o = 1; o < 256; o <<= 1) {
        int tv = (t >= o) ? sc[t - o] : 0;
        __syncthreads();
        sc[t] += tv;
        __syncthreads();
    }
    if (i < N_NODES) {
        int s = bexcl[blockIdx.x] + (sc[t] - v);
        off[i] = s;
        pos[i] = s;
        if (offcnt) offcnt[i] = make_int2(s, v);
        dinv[i] = rsqrtf((float)(v + 1)); // +1 self-loop
    }
}

// builds CSR with PACKED 16B records: ONE global_store_dwordx4 per edge
// (was 3 scattered 4B stores -> 3x fewer random write transactions)
__global__ void k_build(const int* __restrict__ row, const int* __restrict__ col,
                        int* __restrict__ pos, const float* __restrict__ dinv,
                        int4* __restrict__ edge) {
    int e = blockIdx.x * 256 + threadIdx.x;
    if (e < N_EDGES) {
        unsigned r = (unsigned)row[e], c = (unsigned)col[e];
        if (r < N_NODES && c < N_NODES) {
            int slot = atomicAdd(&pos[c], 1);
            edge[slot] = make_int4((int)r, e, __float_as_int(dinv[r]), 0);
        }
    }
}

// -------------------------------------------------- latency-optimized gather
// One wave per destination node. Flat-16: bulk scalar loads of packed edge
// records, then all vector gathers issued in one round. Pad lanes (i >= d,
// wave-uniform compare) get v=0 and are redirected to entry 0's row (L1 hit,
// zero extra HBM traffic -- round-3's range-clamp bug fetched other nodes'
// rows, +92 MB).
// Writes the finished activation row:
//   act[c][0:128]   = dinv[c]*aggX + dinv[c]^2 * X[c]
//   act[c][128:192] = dinv[c]*aggEA   (mode 0 only; layer-invariant)
template<int MODE>
__global__ __launch_bounds__(256) void k_gather(
    const float* __restrict__ X, const float* __restrict__ EAraw,
    const int2* __restrict__ offcnt, const int4* __restrict__ edge,
    const float* __restrict__ dinv, float* __restrict__ act)
{
    int w = threadIdx.x >> 6, l = threadIdx.x & 63;
    int c = blockIdx.x * 4 + w;
    if (c >= N_NODES) return;
    int2 oc = offcnt[c];
    int beg = __builtin_amdgcn_readfirstlane(oc.x);
    int d   = __builtin_amdgcn_readfirstlane(oc.y);
    const float2* X2 = (const float2*)X;

    float2 xc = X2[(size_t)c * 64 + l];   // self row: issue early, overlaps gathers
    float dv = dinv[c];

    // ---- bulk wave-uniform metadata loads (one contiguous 256B record block)
    int sU[16]; float vU[16]; int eU[16];
    #pragma unroll
    for (int i = 0; i < 16; i++) {
        int4 E = edge[beg + i];
        sU[i] = E.x;
        eU[i] = E.y;
        vU[i] = __int_as_float(E.z);
    }
    int s0 = (d > 0) ? sU[0] : 0;      // d==0 -> index 0 (valid row, v=0 anyway)
    int e0 = (d > 0) ? eU[0] : 0;
    #pragma unroll
    for (int i = 0; i < 16; i++) {
        if (i >= d) {                   // wave-uniform scalar select per i
            vU[i] = 0.f;
            sU[i] = s0;
            eU[i] = e0;
        }
    }

    // ---- issue all gathers before any accumulation
    float2 xv[16];
    #pragma unroll
    for (int i = 0; i < 16; i++) xv[i] = X2[(size_t)sU[i] * 64 + l];
    float evv[16];
    if (MODE == 0) {
        #pragma unroll
        for (int i = 0; i < 16; i++) evv[i] = EAraw[(size_t)eU[i] * 64 + l];
    }

    // sequential accumulation (keeps absmax low)
    float a0 = 0.f, a1 = 0.f, ae = 0.f;
    #pragma unroll
    for (int i = 0; i < 16; i++) {
        a0 += vU[i] * xv[i].x;
        a1 += vU[i] * xv[i].y;
        if (MODE == 0) ae += vU[i] * evv[i];
    }

    // ---- rare tail (P(d>16) ~ 0.4% for Poisson(8))
    for (int j = 16; j < d; j++) {
        int4 E = edge[beg + j];
        float v = __int_as_float(E.z);
        float2 x = X2[(size_t)E.x * 64 + l];
        a0 += v * x.x;
        a1 += v * x.y;
        if (MODE == 0) ae += v * EAraw[(size_t)E.y * 64 + l];
    }

    float dv2 = dv * dv;
    float* arow = act + (size_t)c * 192;
    ((float2*)arow)[l] = make_float2(dv * a0 + dv2 * xc.x, dv * a1 + dv2 * xc.y);
    if (MODE == 0) arow[128 + l] = dv * ae;
}

// -------------------------------------------------- LDS-broadcast GEMM (layer 1)
// h1[c] = gelu( act[c][0:192] @ [Wn;We] + bias )
__global__ __launch_bounds__(256, 3) void k_gemm(
    const float* __restrict__ act,
    const float* __restrict__ Wn, const float* __restrict__ We,
    const float* __restrict__ bias, float* __restrict__ out)
{
    __shared__ float sact[64][192];
    int t = threadIdx.x;
    int w = t >> 6, l = t & 63;

    const size_t CAP = (size_t)N_NODES * 192;
    size_t base = (size_t)blockIdx.x * (64 * 192);
    #pragma unroll
    for (int i = 0; i < 12; i++) {
        size_t fi = base + (size_t)(i * 256 + t) * 4;
        float4 v = make_float4(0.f, 0.f, 0.f, 0.f);
        if (fi + 4 <= CAP) v = *(const float4*)(act + fi);
        *(float4*)&sact[0][(i * 256 + t) * 4] = v;
    }
    __syncthreads();

    int row0 = blockIdx.x * 64 + w * 16;
    float acc[16][2] = {};

    const float2* Wn2 = (const float2*)Wn;
    for (int k = 0; k < 128; k += 4) {
        float2 w0 = Wn2[(k + 0) * 64 + l];
        float2 w1 = Wn2[(k + 1) * 64 + l];
        float2 w2 = Wn2[(k + 2) * 64 + l];
        float2 w3 = Wn2[(k + 3) * 64 + l];
        #pragma unroll
        for (int r = 0; r < 16; r++) {
            float4 a = *(const float4*)&sact[w * 16 + r][k];
            acc[r][0] += a.x * w0.x + a.y * w1.x + a.z * w2.x + a.w * w3.x;
            acc[r][1] += a.x * w0.y + a.y * w1.y + a.z * w2.y + a.w * w3.y;
        }
    }
    const float2* We2 = (const float2*)We;
    for (int k = 0; k < 64; k += 4) {
        float2 w0 = We2[(k + 0) * 64 + l];
        float2 w1 = We2[(k + 1) * 64 + l];
        float2 w2 = We2[(k + 2) * 64 + l];
        float2 w3 = We2[(k + 3) * 64 + l];
        #pragma unroll
        for (int r = 0; r < 16; r++) {
            float4 a = *(const float4*)&sact[w * 16 + r][128 + k];
            acc[r][0] += a.x * w0.x + a.y * w1.x + a.z * w2.x + a.w * w3.x;
            acc[r][1] += a.x * w0.y + a.y * w1.y + a.z * w2.y + a.w * w3.y;
        }
    }

    float2 bb = ((const float2*)bias)[l];
    #pragma unroll
    for (int r = 0; r < 16; r++) {
        int c = row0 + r;
        if (c >= N_NODES) break;
        float v0 = acc[r][0] + bb.x;
        float v1 = acc[r][1] + bb.y;
        v0 = 0.5f * v0 * (1.0f + erff(v0 * 0.70710678f)); // exact gelu
        v1 = 0.5f * v1 * (1.0f + erff(v1 * 0.70710678f));
        ((float2*)out)[(size_t)c * 64 + l] = make_float2(v0, v1);
    }
}

// ------------------------- layer-2 GEMM + residual + LayerNorm, fully fused.
// h2 never touches HBM: gelu output written back into the wave's own sact rows
// (wave-private -> no barrier needed), then Wo-GEMM + LN straight to out.
// Saves the 51 MB h2 write + 51 MB h2 read of the split gemm2/k_final pair.
__global__ __launch_bounds__(256, 3) void k_gemm_final(
    const float* __restrict__ act,
    const float* __restrict__ Wn, const float* __restrict__ We,
    const float* __restrict__ bias, const float* __restrict__ x,
    const float* __restrict__ Wo, const float* __restrict__ bo,
    const float* __restrict__ g, const float* __restrict__ lb,
    float* __restrict__ out)
{
    __shared__ float sact[64][192];
    int t = threadIdx.x;
    int w = t >> 6, l = t & 63;

    const size_t CAP = (size_t)N_NODES * 192;
    size_t base = (size_t)blockIdx.x * (64 * 192);
    #pragma unroll
    for (int i = 0; i < 12; i++) {
        size_t fi = base + (size_t)(i * 256 + t) * 4;
        float4 v = make_float4(0.f, 0.f, 0.f, 0.f);
        if (fi + 4 <= CAP) v = *(const float4*)(act + fi);
        *(float4*)&sact[0][(i * 256 + t) * 4] = v;
    }
    __syncthreads();

    int row0 = blockIdx.x * 64 + w * 16;
    float acc[16][2] = {};

    // ---- phase 2: h2 = gelu(act @ [Wn;We] + b)  (identical order to k_gemm)
    const float2* Wn2 = (const float2*)Wn;
    for (int k = 0; k < 128; k += 4) {
        float2 w0 = Wn2[(k + 0) * 64 + l];
        float2 w1 = Wn2[(k + 1) * 64 + l];
        float2 w2 = Wn2[(k + 2) * 64 + l];
        float2 w3 = Wn2[(k + 3) * 64 + l];
        #pragma unroll
        for (int r = 0; r < 16; r++) {
            float4 a = *(const float4*)&sact[w * 16 + r][k];
            acc[r][0] += a.x * w0.x + a.y * w1.x + a.z * w2.x + a.w * w3.x;
            acc[r][1] += a.x * w0.y + a.y * w1.y + a.z * w2.y + a.w * w3.y;
        }
    }
    const float2* We2 = (const float2*)We;
    for (int k = 0; k < 64; k += 4) {
        float2 w0 = We2[(k + 0) * 64 + l];
        float2 w1 = We2[(k + 1) * 64 + l];
        float2 w2 = We2[(k + 2) * 64 + l];
        float2 w3 = We2[(k + 3) * 64 + l];
        #pragma unroll
        for (int r = 0; r < 16; r++) {
            float4 a = *(const float4*)&sact[w * 16 + r][128 + k];
            acc[r][0] += a.x * w0.x + a.y * w1.x + a.z * w2.x + a.w * w3.x;
            acc[r][1] += a.x * w0.y + a.y * w1.y + a.z * w2.y + a.w * w3.y;
        }
    }

    // gelu -> stage h2 into the wave's OWN rows (wave-private: compiler's
    // lgkmcnt handles the ds_write->ds_read dependency, no barrier needed)
    float2 bb = ((const float2*)bias)[l];
    #pragma unroll
    for (int r = 0; r < 16; r++) {
        float v0 = acc[r][0] + bb.x;
        float v1 = acc[r][1] + bb.y;
        v0 = 0.5f * v0 * (1.0f + erff(v0 * 0.70710678f));
        v1 = 0.5f * v1 * (1.0f + erff(v1 * 0.70710678f));
        sact[w * 16 + r][2 * l]     = v0;
        sact[w * 16 + r][2 * l + 1] = v1;
        acc[r][0] = 0.f;                // reuse acc for phase 3
        acc[r][1] = 0.f;
    }

    // ---- phase 3: out = LayerNorm(h2 @ Wo + bo + x)
    const float2* Wo2 = (const float2*)Wo;
    for (int k = 0; k < 128; k += 4) {
        float2 w0 = Wo2[(k + 0) * 64 + l];
        float2 w1 = Wo2[(k + 1) * 64 + l];
        float2 w2 = Wo2[(k + 2) * 64 + l];
        float2 w3 = Wo2[(k + 3) * 64 + l];
        #pragma unroll
        for (int r = 0; r < 16; r++) {
            float4 a = *(const float4*)&sact[w * 16 + r][k];
            acc[r][0] += a.x * w0.x + a.y * w1.x + a.z * w2.x + a.w * w3.x;
            acc[r][1] += a.x * w0.y + a.y * w1.y + a.z * w2.y + a.w * w3.y;
        }
    }

    float2 bov = ((const float2*)bo)[l];
    float2 gv  = ((const float2*)g)[l];
    float2 lbv = ((const float2*)lb)[l];
    const float2* X2 = (const float2*)x;

    #pragma unroll
    for (int r = 0; r < 16; r++) {
        int c = row0 + r;
        bool ok = (c < N_NODES);
        float2 xv = ok ? X2[(size_t)c * 64 + l] : make_float2(0.f, 0.f);
        float v0 = acc[r][0] + bov.x + xv.x;
        float v1 = acc[r][1] + bov.y + xv.y;
        float s = v0 + v1;
        #pragma unroll
        for (int o = 32; o; o >>= 1) s += __shfl_xor(s, o, 64);
        float mu = s * (1.0f / 128.0f);
        float d0 = v0 - mu, d1 = v1 - mu;
        float sq = d0 * d0 + d1 * d1;
        #pragma unroll
        for (int o = 32; o; o >>= 1) sq += __shfl_xor(sq, o, 64);
        float rs = rsqrtf(sq * (1.0f / 128.0f) + 1e-5f);
        if (ok) {
            float2 ov;
            ov.x = d0 * rs * gv.x + lbv.x;
            ov.y = d1 * rs * gv.y + lbv.y;
            ((float2*)out)[(size_t)c * 64 + l] = ov;
        }
    }
}

// --------------------- fused fallback (proven path, small workspace)
__global__ __launch_bounds__(256) void k_layer(
    const float* __restrict__ X, const float* __restrict__ EAraw,
    const float* __restrict__ EaIn, float* __restrict__ EaOut,
    const int* __restrict__ off, const int* __restrict__ cnt,
    const int4* __restrict__ edge, const float* __restrict__ dinv,
    const float* __restrict__ Wn, const float* __restrict__ We,
    const float* __restrict__ bias, float* __restrict__ out, int mode)
{
    __shared__ float act[4][4][192];
    int w = threadIdx.x >> 6, l = threadIdx.x & 63;
    int row0 = blockIdx.x * 16 + w * 4;

    for (int r = 0; r < 4; r++) {
        int c = row0 + r;
        int beg = off[c];
        int d = cnt[c];
        float a0 = 0.f, a1 = 0.f, ae = 0.f;
        for (int j = 0; j < d; j++) {
            int4 E = edge[beg + j];
            unsigned s = (unsigned)E.x;
            if (s >= N_NODES) continue;
            float sv = __int_as_float(E.z);
            float2 xv = ((const float2*)X)[s * 64 + l];
            a0 += sv * xv.x;
            a1 += sv * xv.y;
            if (mode == 0) {
                unsigned e = (unsigned)E.y;
                if (e < N_EDGES) ae += sv * EAraw[e * 64 + l];
            }
        }
        float dv = dinv[c], dv2 = dv * dv;
        float2 xc = ((const float2*)X)[c * 64 + l];
        act[w][r][2 * l]     = dv * a0 + dv2 * xc.x;
        act[w][r][2 * l + 1] = dv * a1 + dv2 * xc.y;
        if (mode == 0) {
            act[w][r][128 + l] = dv * ae;
            EaOut[c * 64 + l] = ae;
        } else {
            act[w][r][128 + l] = dv * EaIn[c * 64 + l];
        }
    }
    __syncthreads();

    float acc[4][2] = {};
    for (int k = 0; k < 128; k++) {
        float2 wv = ((const float2*)Wn)[k * 64 + l];
        #pragma unroll
        for (int r = 0; r < 4; r++) {
            float a = act[w][r][k];
            acc[r][0] += a * wv.x;
            acc[r][1] += a * wv.y;
        }
    }
    for (int k = 0; k < 64; k++) {
        float2 wv = ((const float2*)We)[k * 64 + l];
        #pragma unroll
        for (int r = 0; r < 4; r++) {
            float a = act[w][r][128 + k];
            acc[r][0] += a * wv.x;
            acc[r][1] += a * wv.y;
        }
    }

    float2 bb = ((const float2*)bias)[l];
    for (int r = 0; r < 4; r++) {
        float v0 = acc[r][0] + bb.x;
        float v1 = acc[r][1] + bb.y;
        v0 = 0.5f * v0 * (1.0f + erff(v0 * 0.70710678f));
        v1 = 0.5f * v1 * (1.0f + erff(v1 * 0.70710678f));
        ((float2*)out)[(row0 + r) * 64 + l] = make_float2(v0, v1);
    }
}

// ------------------------------------ final (fallback path only)
__global__ __launch_bounds__(256) void k_final(
    const float* __restrict__ h2, const float* __restrict__ x,
    const float* __restrict__ Wo, const float* __restrict__ bo,
    const float* __restrict__ g, const float* __restrict__ lb,
    float* __restrict__ out)
{
    __shared__ float lds[4][4][128];
    int w = threadIdx.x >> 6, l = threadIdx.x & 63;
    int row0 = blockIdx.x * 16 + w * 4;

    for (int r = 0; r < 4; r++) {
        int c = row0 + r;
        float2 hv = ((const float2*)h2)[(size_t)c * 64 + l];
        lds[w][r][2 * l]     = hv.x;
        lds[w][r][2 * l + 1] = hv.y;
    }
    __syncthreads();

    float acc[4][2] = {};
    const float2* Wo2 = (const float2*)Wo;
    for (int k = 0; k < 128; k += 4) {
        float2 w0 = Wo2[(k + 0) * 64 + l];
        float2 w1 = Wo2[(k + 1) * 64 + l];
        float2 w2 = Wo2[(k + 2) * 64 + l];
        float2 w3 = Wo2[(k + 3) * 64 + l];
        #pragma unroll
        for (int r = 0; r < 4; r++) {
            float4 a = *(const float4*)&lds[w][r][k];
            acc[r][0] += a.x * w0.x + a.y * w1.x + a.z * w2.x + a.w * w3.x;
            acc[r][1] += a.x * w0.y + a.y * w1.y + a.z * w2.y + a.w * w3.y;
        }
    }

    float2 bov = ((const float2*)bo)[l];
    float2 gv  = ((const float2*)g)[l];
    float2 lbv = ((const float2*)lb)[l];

    for (int r = 0; r < 4; r++) {
        int c = row0 + r;
        float2 xv = ((const float2*)x)[(size_t)c * 64 + l];
        float v0 = acc[r][0] + bov.x + xv.x;
        float v1 = acc[r][1] + bov.y + xv.y;
        float s = v0 + v1;
        #pragma unroll
        for (int o = 32; o; o >>= 1) s += __shfl_xor(s, o, 64);
        float mu = s * (1.0f / 128.0f);
        float d0 = v0 - mu, d1 = v1 - mu;
        float sq = d0 * d0 + d1 * d1;
        #pragma unroll
        for (int o = 32; o; o >>= 1) sq += __shfl_xor(sq, o, 64);
        float rs = rsqrtf(sq * (1.0f / 128.0f) + 1e-5f);
        float2 ov;
        ov.x = d0 * rs * gv.x + lbv.x;
        ov.y = d1 * rs * gv.y + lbv.y;
        ((float2*)out)[(size_t)c * 64 + l] = ov;
    }
}

extern "C" void kernel_launch(void* const* d_in, const int* in_sizes, int n_in,
                              void* d_out, int out_size, void* d_ws, size_t ws_size,
                              hipStream_t stream)
{
    const float* x   = (const float*)d_in[0];
    const int*   ei  = (const int*)d_in[1];
    const float* ea  = (const float*)d_in[2];
    // d_in[3..6] (W_qkv, b_qkv, W_ek, b_ek) are dead code in the reference.
    const float* Wn1 = (const float*)d_in[7];
    const float* We1 = (const float*)d_in[8];
    const float* b1  = (const float*)d_in[9];
    const float* Wn2 = (const float*)d_in[10];
    const float* We2 = (const float*)d_in[11];
    const float* b2  = (const float*)d_in[12];
    const float* Wo  = (const float*)d_in[13];
    const float* bo  = (const float*)d_in[14];
    const float* lng = (const float*)d_in[15];
    const float* lnb = (const float*)d_in[16];
    const int* row = ei;
    const int* col = ei + N_EDGES;

    char* ws = (char*)d_ws;
    size_t off_b = 0;
    auto alloc = [&](size_t bytes) {
        void* p = ws + off_b;
        off_b += (bytes + 255) & ~(size_t)255;
        return p;
    };
    // ---- common workspace: CSR (packed 16B edge records, padded +16) + h1
    int*   cnt   = (int*)  alloc((size_t)N_NODES * 4);
    int*   off   = (int*)  alloc((size_t)N_NODES * 4);
    int*   pos   = (int*)  alloc((size_t)N_NODES * 4);
    int*   bsum  = (int*)  alloc((size_t)NBLK * 4);
    int*   bexcl = (int*)  alloc((size_t)NBLK * 4);
    float* dinv  = (float*)alloc((size_t)N_NODES * 4);
    int4*  edge  = (int4*) alloc((size_t)(N_EDGES + 16) * 16);
    float* h1    = (float*)alloc((size_t)N_NODES * 128 * 4);
    size_t common_end = off_b;

    // ---- split-path extras: offcnt + act[N][192]
    int2*  offcnt = (int2*) alloc((size_t)N_NODES * 8);
    float* act    = (float*)alloc((size_t)N_NODES * 192 * 4);
    size_t split_end = off_b;

    // ---- fused-path extras overlap the split-path region (paths exclusive)
    float* Ea = (float*)(ws + common_end);
    size_t fused_end = common_end + (((size_t)N_NODES * 64 * 4 + 255) & ~(size_t)255);

    bool use_split = (split_end <= ws_size);
    if (!use_split && fused_end > ws_size) return; // finite-wrong signature, diagnosable

    float* h2 = (float*)d_out;    // fallback path stages h2 in d_out

    hipMemsetAsync(cnt, 0, (size_t)N_NODES * 4, stream);

    k_count     <<<(N_EDGES + 255) / 256, 256, 0, stream>>>(col, cnt);
    k_blocksum  <<<NBLK, 256, 0, stream>>>(cnt, bsum);
    k_scanblocks<<<1, 512, 0, stream>>>(bsum, bexcl);
    k_offsets   <<<NBLK, 256, 0, stream>>>(cnt, bexcl, off, pos,
                                           use_split ? offcnt : nullptr, dinv);
    k_build     <<<(N_EDGES + 255) / 256, 256, 0, stream>>>(row, col, pos, dinv, edge);

    if (use_split) {
        k_gather<0><<<(N_NODES + 3) / 4, 256, 0, stream>>>(x, ea, offcnt,
                                                           edge, dinv, act);
        k_gemm     <<<(N_NODES + 63) / 64, 256, 0, stream>>>(act, Wn1, We1, b1, h1);
        k_gather<1><<<(N_NODES + 3) / 4, 256, 0, stream>>>(h1, nullptr, offcnt,
                                                           edge, dinv, act);
        k_gemm_final<<<(N_NODES + 63) / 64, 256, 0, stream>>>(
            act, Wn2, We2, b2, x, Wo, bo, lng, lnb, (float*)d_out);
    } else {
        k_layer<<<N_NODES / 16, 256, 0, stream>>>(x, ea, nullptr, Ea,
                                                  off, cnt, edge, dinv,
                                                  Wn1, We1, b1, h1, 0);
        k_layer<<<N_NODES / 16, 256, 0, stream>>>(h1, nullptr, Ea, nullptr,
                                                  off, cnt, edge, dinv,
                                                  Wn2, We2, b2, h2, 1);
        k_final<<<N_NODES / 16, 256, 0, stream>>>(h2, x, Wo, bo, lng, lnb, (float*)d_out);
    }
}

// Round 6
// 830.521 us; speedup vs baseline: 1.1363x; 1.0276x over previous
//
#include <hip/hip_runtime.h>
#include <math.h>

#define N_NODES 100000
#define N_EDGES 800000
#define NBLK 391  // ceil(N_NODES/256)

// ----------------------------------------------------------- CSR construction
__global__ void k_count(const int* __restrict__ col, int* __restrict__ cnt) {
    int e = blockIdx.x * 256 + threadIdx.x;
    if (e < N_EDGES) {
        unsigned c = (unsigned)col[e];
        if (c < N_NODES) atomicAdd(&cnt[c], 1);
    }
}

__global__ void k_blocksum(const int* __restrict__ cnt, int* __restrict__ bsum) {
    __shared__ int sc[256];
    int t = threadIdx.x, i = blockIdx.x * 256 + t;
    sc[t] = (i < N_NODES) ? cnt[i] : 0;
    __syncthreads();
    for (int o = 128; o; o >>= 1) {
        if (t < o) sc[t] += sc[t + o];
        __syncthreads();
    }
    if (t == 0) bsum[blockIdx.x] = sc[0];
}

// one-block parallel scan over the 391 block sums
__global__ void k_scanblocks(const int* __restrict__ bsum, int* __restrict__ bexcl) {
    __shared__ int s[512];
    int t = threadIdx.x;
    s[t] = (t < NBLK) ? bsum[t] : 0;
    __syncthreads();
    for (int o = 1; o < 512; o <<= 1) {
        int v = (t >= o) ? s[t - o] : 0;
        __syncthreads();
        s[t] += v;
        __syncthreads();
    }
    if (t < NBLK) bexcl[t] = t ? s[t - 1] : 0;
}

// offsets + pos + packed {off,cnt} + dinv (k_dinv folded in)
__global__ void k_offsets(const int* __restrict__ cnt, const int* __restrict__ bexcl,
                          int* __restrict__ off, int* __restrict__ pos,
                          int2* __restrict__ offcnt, float* __restrict__ dinv) {
    __shared__ int sc[256];
    int t = threadIdx.x, i = blockIdx.x * 256 + t;
    int v = (i < N_NODES) ? cnt[i] : 0;
    sc[t] = v;
    __syncthreads();
    for (int o = 1; o < 256; o <<= 1) {
        int tv = (t >= o) ? sc[t - o] : 0;
        __syncthreads();
        sc[t] += tv;
        __syncthreads();
    }
    if (i < N_NODES) {
        int s = bexcl[blockIdx.x] + (sc[t] - v);
        off[i] = s;
        pos[i] = s;
        if (offcnt) offcnt[i] = make_int2(s, v);
        dinv[i] = rsqrtf((float)(v + 1)); // +1 self-loop
    }
}

// builds CSR with PACKED 16B records: ONE global_store_dwordx4 per edge
__global__ void k_build(const int* __restrict__ row, const int* __restrict__ col,
                        int* __restrict__ pos, const float* __restrict__ dinv,
                        int4* __restrict__ edge) {
    int e = blockIdx.x * 256 + threadIdx.x;
    if (e < N_EDGES) {
        unsigned r = (unsigned)row[e], c = (unsigned)col[e];
        if (r < N_NODES && c < N_NODES) {
            int slot = atomicAdd(&pos[c], 1);
            edge[slot] = make_int4((int)r, e, __float_as_int(dinv[r]), 0);
        }
    }
}

// -------------------------------------------------- latency-optimized gather
// One wave per destination node. Flat-16: bulk scalar loads of packed edge
// records, then all vector gathers issued in one round. Pad lanes (i >= d)
// get v=0 and are redirected to entry 0's row (L1 hit, zero extra HBM).
// Writes the finished activation row:
//   act[c][0:128]   = dinv[c]*aggX + dinv[c]^2 * X[c]
//   act[c][128:192] = dinv[c]*aggEA   (mode 0 only; layer-invariant)
template<int MODE>
__global__ __launch_bounds__(256) void k_gather(
    const float* __restrict__ X, const float* __restrict__ EAraw,
    const int2* __restrict__ offcnt, const int4* __restrict__ edge,
    const float* __restrict__ dinv, float* __restrict__ act)
{
    int w = threadIdx.x >> 6, l = threadIdx.x & 63;
    int c = blockIdx.x * 4 + w;
    if (c >= N_NODES) return;
    int2 oc = offcnt[c];
    int beg = __builtin_amdgcn_readfirstlane(oc.x);
    int d   = __builtin_amdgcn_readfirstlane(oc.y);
    const float2* X2 = (const float2*)X;

    float2 xc = X2[(size_t)c * 64 + l];   // self row: issue early, overlaps gathers
    float dv = dinv[c];

    // ---- bulk wave-uniform metadata loads (one contiguous 256B record block)
    int sU[16]; float vU[16]; int eU[16];
    #pragma unroll
    for (int i = 0; i < 16; i++) {
        int4 E = edge[beg + i];
        sU[i] = E.x;
        eU[i] = E.y;
        vU[i] = __int_as_float(E.z);
    }
    int s0 = (d > 0) ? sU[0] : 0;      // d==0 -> index 0 (valid row, v=0 anyway)
    int e0 = (d > 0) ? eU[0] : 0;
    #pragma unroll
    for (int i = 0; i < 16; i++) {
        if (i >= d) {                   // wave-uniform scalar select per i
            vU[i] = 0.f;
            sU[i] = s0;
            eU[i] = e0;
        }
    }

    // ---- issue all gathers before any accumulation
    float2 xv[16];
    #pragma unroll
    for (int i = 0; i < 16; i++) xv[i] = X2[(size_t)sU[i] * 64 + l];
    float evv[16];
    if (MODE == 0) {
        #pragma unroll
        for (int i = 0; i < 16; i++) evv[i] = EAraw[(size_t)eU[i] * 64 + l];
    }

    // sequential accumulation (keeps absmax low)
    float a0 = 0.f, a1 = 0.f, ae = 0.f;
    #pragma unroll
    for (int i = 0; i < 16; i++) {
        a0 += vU[i] * xv[i].x;
        a1 += vU[i] * xv[i].y;
        if (MODE == 0) ae += vU[i] * evv[i];
    }

    // ---- rare tail (P(d>16) ~ 0.4% for Poisson(8))
    for (int j = 16; j < d; j++) {
        int4 E = edge[beg + j];
        float v = __int_as_float(E.z);
        float2 x = X2[(size_t)E.x * 64 + l];
        a0 += v * x.x;
        a1 += v * x.y;
        if (MODE == 0) ae += v * EAraw[(size_t)E.y * 64 + l];
    }

    float dv2 = dv * dv;
    float* arow = act + (size_t)c * 192;
    ((float2*)arow)[l] = make_float2(dv * a0 + dv2 * xc.x, dv * a1 + dv2 * xc.y);
    if (MODE == 0) arow[128 + l] = dv * ae;
}

// -------------------------------------------------- LDS-broadcast GEMM (layer 1)
// h1[c] = gelu( act[c][0:192] @ [Wn;We] + bias )
// 2-wave / 32-row / 24KB-LDS blocks (6 blocks/CU -> 3 waves/SIMD, was 25% occ)
// + explicit 1-deep weight prefetch (n0..n3 hold k+4 while k's FMAs run).
// 100000 = 3125*32 exactly: no bounds checks anywhere.
__global__ __launch_bounds__(128, 3) void k_gemm(
    const float* __restrict__ act,
    const float* __restrict__ Wn, const float* __restrict__ We,
    const float* __restrict__ bias, float* __restrict__ out)
{
    __shared__ float sact[32][192];
    int t = threadIdx.x;
    int w = t >> 6, l = t & 63;

    size_t base = (size_t)blockIdx.x * (32 * 192);
    #pragma unroll
    for (int i = 0; i < 12; i++) {
        *(float4*)&sact[0][(i * 128 + t) * 4] =
            *(const float4*)(act + base + (size_t)(i * 128 + t) * 4);
    }
    __syncthreads();

    int row0 = blockIdx.x * 32 + w * 16;
    float acc[16][2] = {};

    const float2* Wn2 = (const float2*)Wn;
    const float2* We2 = (const float2*)We;

    float2 n0 = Wn2[l], n1 = Wn2[64 + l], n2 = Wn2[128 + l], n3 = Wn2[192 + l];
    for (int k = 0; k < 192; k += 4) {
        float2 w0 = n0, w1 = n1, w2 = n2, w3 = n3;
        int kn = k + 4;
        if (kn < 192) {
            const float2* Wp = (kn < 128) ? (Wn2 + (size_t)kn * 64)
                                          : (We2 + (size_t)(kn - 128) * 64);
            n0 = Wp[l]; n1 = Wp[64 + l]; n2 = Wp[128 + l]; n3 = Wp[192 + l];
        }
        #pragma unroll
        for (int r = 0; r < 16; r++) {
            float4 a = *(const float4*)&sact[w * 16 + r][k];
            acc[r][0] += a.x * w0.x + a.y * w1.x + a.z * w2.x + a.w * w3.x;
            acc[r][1] += a.x * w0.y + a.y * w1.y + a.z * w2.y + a.w * w3.y;
        }
    }

    float2 bb = ((const float2*)bias)[l];
    #pragma unroll
    for (int r = 0; r < 16; r++) {
        float v0 = acc[r][0] + bb.x;
        float v1 = acc[r][1] + bb.y;
        v0 = 0.5f * v0 * (1.0f + erff(v0 * 0.70710678f)); // exact gelu
        v1 = 0.5f * v1 * (1.0f + erff(v1 * 0.70710678f));
        ((float2*)out)[(size_t)(row0 + r) * 64 + l] = make_float2(v0, v1);
    }
}

// ------------------------- layer-2 GEMM + residual + LayerNorm, fully fused.
// Same 2-wave/32-row structure. The weight prefetch chain runs Wn -> We -> Wo
// across phase boundaries: Wo's k=0 weights are loading while gelu executes.
// h2 stays in the wave's own LDS rows (DS in-order within a wave: no barrier).
__global__ __launch_bounds__(128, 3) void k_gemm_final(
    const float* __restrict__ act,
    const float* __restrict__ Wn, const float* __restrict__ We,
    const float* __restrict__ bias, const float* __restrict__ x,
    const float* __restrict__ Wo, const float* __restrict__ bo,
    const float* __restrict__ g, const float* __restrict__ lb,
    float* __restrict__ out)
{
    __shared__ float sact[32][192];
    int t = threadIdx.x;
    int w = t >> 6, l = t & 63;

    size_t base = (size_t)blockIdx.x * (32 * 192);
    #pragma unroll
    for (int i = 0; i < 12; i++) {
        *(float4*)&sact[0][(i * 128 + t) * 4] =
            *(const float4*)(act + base + (size_t)(i * 128 + t) * 4);
    }
    __syncthreads();

    int row0 = blockIdx.x * 32 + w * 16;
    float acc[16][2] = {};

    const float2* Wn2 = (const float2*)Wn;
    const float2* We2 = (const float2*)We;
    const float2* Wo2 = (const float2*)Wo;

    // ---- phase 2: h2 = gelu(act @ [Wn;We] + b)
    float2 n0 = Wn2[l], n1 = Wn2[64 + l], n2 = Wn2[128 + l], n3 = Wn2[192 + l];
    for (int k = 0; k < 192; k += 4) {
        float2 w0 = n0, w1 = n1, w2 = n2, w3 = n3;
        int kn = k + 4;
        const float2* Wp = (kn < 128) ? (Wn2 + (size_t)kn * 64)
                         : (kn < 192) ? (We2 + (size_t)(kn - 128) * 64)
                                      : Wo2;          // kn==192: prefetch Wo k=0..3
        n0 = Wp[l]; n1 = Wp[64 + l]; n2 = Wp[128 + l]; n3 = Wp[192 + l];
        #pragma unroll
        for (int r = 0; r < 16; r++) {
            float4 a = *(const float4*)&sact[w * 16 + r][k];
            acc[r][0] += a.x * w0.x + a.y * w1.x + a.z * w2.x + a.w * w3.x;
            acc[r][1] += a.x * w0.y + a.y * w1.y + a.z * w2.y + a.w * w3.y;
        }
    }

    // gelu -> h2 into the wave's OWN rows (Wo prefetch in flight meanwhile)
    float2 bb = ((const float2*)bias)[l];
    #pragma unroll
    for (int r = 0; r < 16; r++) {
        float v0 = acc[r][0] + bb.x;
        float v1 = acc[r][1] + bb.y;
        v0 = 0.5f * v0 * (1.0f + erff(v0 * 0.70710678f));
        v1 = 0.5f * v1 * (1.0f + erff(v1 * 0.70710678f));
        sact[w * 16 + r][2 * l]     = v0;
        sact[w * 16 + r][2 * l + 1] = v1;
        acc[r][0] = 0.f;                // reuse acc for phase 3
        acc[r][1] = 0.f;
    }

    // ---- phase 3: out = LayerNorm(h2 @ Wo + bo + x)
    for (int k = 0; k < 128; k += 4) {
        float2 w0 = n0, w1 = n1, w2 = n2, w3 = n3;
        int kn = k + 4;
        if (kn < 128) {
            const float2* Wp = Wo2 + (size_t)kn * 64;
            n0 = Wp[l]; n1 = Wp[64 + l]; n2 = Wp[128 + l]; n3 = Wp[192 + l];
        }
        #pragma unroll
        for (int r = 0; r < 16; r++) {
            float4 a = *(const float4*)&sact[w * 16 + r][k];
            acc[r][0] += a.x * w0.x + a.y * w1.x + a.z * w2.x + a.w * w3.x;
            acc[r][1] += a.x * w0.y + a.y * w1.y + a.z * w2.y + a.w * w3.y;
        }
    }

    float2 bov = ((const float2*)bo)[l];
    float2 gv  = ((const float2*)g)[l];
    float2 lbv = ((const float2*)lb)[l];
    const float2* X2 = (const float2*)x;

    #pragma unroll
    for (int r = 0; r < 16; r++) {
        int c = row0 + r;
        float2 xv = X2[(size_t)c * 64 + l];
        float v0 = acc[r][0] + bov.x + xv.x;
        float v1 = acc[r][1] + bov.y + xv.y;
        float s = v0 + v1;
        #pragma unroll
        for (int o = 32; o; o >>= 1) s += __shfl_xor(s, o, 64);
        float mu = s * (1.0f / 128.0f);
        float d0 = v0 - mu, d1 = v1 - mu;
        float sq = d0 * d0 + d1 * d1;
        #pragma unroll
        for (int o = 32; o; o >>= 1) sq += __shfl_xor(sq, o, 64);
        float rs = rsqrtf(sq * (1.0f / 128.0f) + 1e-5f);
        float2 ov;
        ov.x = d0 * rs * gv.x + lbv.x;
        ov.y = d1 * rs * gv.y + lbv.y;
        ((float2*)out)[(size_t)c * 64 + l] = ov;
    }
}

// --------------------- fused fallback (proven path, small workspace)
__global__ __launch_bounds__(256) void k_layer(
    const float* __restrict__ X, const float* __restrict__ EAraw,
    const float* __restrict__ EaIn, float* __restrict__ EaOut,
    const int* __restrict__ off, const int* __restrict__ cnt,
    const int4* __restrict__ edge, const float* __restrict__ dinv,
    const float* __restrict__ Wn, const float* __restrict__ We,
    const float* __restrict__ bias, float* __restrict__ out, int mode)
{
    __shared__ float act[4][4][192];
    int w = threadIdx.x >> 6, l = threadIdx.x & 63;
    int row0 = blockIdx.x * 16 + w * 4;

    for (int r = 0; r < 4; r++) {
        int c = row0 + r;
        int beg = off[c];
        int d = cnt[c];
        float a0 = 0.f, a1 = 0.f, ae = 0.f;
        for (int j = 0; j < d; j++) {
            int4 E = edge[beg + j];
            unsigned s = (unsigned)E.x;
            if (s >= N_NODES) continue;
            float sv = __int_as_float(E.z);
            float2 xv = ((const float2*)X)[s * 64 + l];
            a0 += sv * xv.x;
            a1 += sv * xv.y;
            if (mode == 0) {
                unsigned e = (unsigned)E.y;
                if (e < N_EDGES) ae += sv * EAraw[e * 64 + l];
            }
        }
        float dv = dinv[c], dv2 = dv * dv;
        float2 xc = ((const float2*)X)[c * 64 + l];
        act[w][r][2 * l]     = dv * a0 + dv2 * xc.x;
        act[w][r][2 * l + 1] = dv * a1 + dv2 * xc.y;
        if (mode == 0) {
            act[w][r][128 + l] = dv * ae;
            EaOut[c * 64 + l] = ae;
        } else {
            act[w][r][128 + l] = dv * EaIn[c * 64 + l];
        }
    }
    __syncthreads();

    float acc[4][2] = {};
    for (int k = 0; k < 128; k++) {
        float2 wv = ((const float2*)Wn)[k * 64 + l];
        #pragma unroll
        for (int r = 0; r < 4; r++) {
            float a = act[w][r][k];
            acc[r][0] += a * wv.x;
            acc[r][1] += a * wv.y;
        }
    }
    for (int k = 0; k < 64; k++) {
        float2 wv = ((const float2*)We)[k * 64 + l];
        #pragma unroll
        for (int r = 0; r < 4; r++) {
            float a = act[w][r][128 + k];
            acc[r][0] += a * wv.x;
            acc[r][1] += a * wv.y;
        }
    }

    float2 bb = ((const float2*)bias)[l];
    for (int r = 0; r < 4; r++) {
        float v0 = acc[r][0] + bb.x;
        float v1 = acc[r][1] + bb.y;
        v0 = 0.5f * v0 * (1.0f + erff(v0 * 0.70710678f));
        v1 = 0.5f * v1 * (1.0f + erff(v1 * 0.70710678f));
        ((float2*)out)[(row0 + r) * 64 + l] = make_float2(v0, v1);
    }
}

// ------------------------------------ final (fallback path only)
__global__ __launch_bounds__(256) void k_final(
    const float* __restrict__ h2, const float* __restrict__ x,
    const float* __restrict__ Wo, const float* __restrict__ bo,
    const float* __restrict__ g, const float* __restrict__ lb,
    float* __restrict__ out)
{
    __shared__ float lds[4][4][128];
    int w = threadIdx.x >> 6, l = threadIdx.x & 63;
    int row0 = blockIdx.x * 16 + w * 4;

    for (int r = 0; r < 4; r++) {
        int c = row0 + r;
        float2 hv = ((const float2*)h2)[(size_t)c * 64 + l];
        lds[w][r][2 * l]     = hv.x;
        lds[w][r][2 * l + 1] = hv.y;
    }
    __syncthreads();

    float acc[4][2] = {};
    const float2* Wo2 = (const float2*)Wo;
    for (int k = 0; k < 128; k += 4) {
        float2 w0 = Wo2[(k + 0) * 64 + l];
        float2 w1 = Wo2[(k + 1) * 64 + l];
        float2 w2 = Wo2[(k + 2) * 64 + l];
        float2 w3 = Wo2[(k + 3) * 64 + l];
        #pragma unroll
        for (int r = 0; r < 4; r++) {
            float4 a = *(const float4*)&lds[w][r][k];
            acc[r][0] += a.x * w0.x + a.y * w1.x + a.z * w2.x + a.w * w3.x;
            acc[r][1] += a.x * w0.y + a.y * w1.y + a.z * w2.y + a.w * w3.y;
        }
    }

    float2 bov = ((const float2*)bo)[l];
    float2 gv  = ((const float2*)g)[l];
    float2 lbv = ((const float2*)lb)[l];

    for (int r = 0; r < 4; r++) {
        int c = row0 + r;
        float2 xv = ((const float2*)x)[(size_t)c * 64 + l];
        float v0 = acc[r][0] + bov.x + xv.x;
        float v1 = acc[r][1] + bov.y + xv.y;
        float s = v0 + v1;
        #pragma unroll
        for (int o = 32; o; o >>= 1) s += __shfl_xor(s, o, 64);
        float mu = s * (1.0f / 128.0f);
        float d0 = v0 - mu, d1 = v1 - mu;
        float sq = d0 * d0 + d1 * d1;
        #pragma unroll
        for (int o = 32; o; o >>= 1) sq += __shfl_xor(sq, o, 64);
        float rs = rsqrtf(sq * (1.0f / 128.0f) + 1e-5f);
        float2 ov;
        ov.x = d0 * rs * gv.x + lbv.x;
        ov.y = d1 * rs * gv.y + lbv.y;
        ((float2*)out)[(size_t)c * 64 + l] = ov;
    }
}

extern "C" void kernel_launch(void* const* d_in, const int* in_sizes, int n_in,
                              void* d_out, int out_size, void* d_ws, size_t ws_size,
                              hipStream_t stream)
{
    const float* x   = (const float*)d_in[0];
    const int*   ei  = (const int*)d_in[1];
    const float* ea  = (const float*)d_in[2];
    // d_in[3..6] (W_qkv, b_qkv, W_ek, b_ek) are dead code in the reference.
    const float* Wn1 = (const float*)d_in[7];
    const float* We1 = (const float*)d_in[8];
    const float* b1  = (const float*)d_in[9];
    const float* Wn2 = (const float*)d_in[10];
    const float* We2 = (const float*)d_in[11];
    const float* b2  = (const float*)d_in[12];
    const float* Wo  = (const float*)d_in[13];
    const float* bo  = (const float*)d_in[14];
    const float* lng = (const float*)d_in[15];
    const float* lnb = (const float*)d_in[16];
    const int* row = ei;
    const int* col = ei + N_EDGES;

    char* ws = (char*)d_ws;
    size_t off_b = 0;
    auto alloc = [&](size_t bytes) {
        void* p = ws + off_b;
        off_b += (bytes + 255) & ~(size_t)255;
        return p;
    };
    // ---- common workspace: CSR (packed 16B edge records, padded +16) + h1
    int*   cnt   = (int*)  alloc((size_t)N_NODES * 4);
    int*   off   = (int*)  alloc((size_t)N_NODES * 4);
    int*   pos   = (int*)  alloc((size_t)N_NODES * 4);
    int*   bsum  = (int*)  alloc((size_t)NBLK * 4);
    int*   bexcl = (int*)  alloc((size_t)NBLK * 4);
    float* dinv  = (float*)alloc((size_t)N_NODES * 4);
    int4*  edge  = (int4*) alloc((size_t)(N_EDGES + 16) * 16);
    float* h1    = (float*)alloc((size_t)N_NODES * 128 * 4);
    size_t common_end = off_b;

    // ---- split-path extras: offcnt + act[N][192]
    int2*  offcnt = (int2*) alloc((size_t)N_NODES * 8);
    float* act    = (float*)alloc((size_t)N_NODES * 192 * 4);
    size_t split_end = off_b;

    // ---- fused-path extras overlap the split-path region (paths exclusive)
    float* Ea = (float*)(ws + common_end);
    size_t fused_end = common_end + (((size_t)N_NODES * 64 * 4 + 255) & ~(size_t)255);

    bool use_split = (split_end <= ws_size);
    if (!use_split && fused_end > ws_size) return; // finite-wrong signature, diagnosable

    float* h2 = (float*)d_out;    // fallback path stages h2 in d_out

    hipMemsetAsync(cnt, 0, (size_t)N_NODES * 4, stream);

    k_count     <<<(N_EDGES + 255) / 256, 256, 0, stream>>>(col, cnt);
    k_blocksum  <<<NBLK, 256, 0, stream>>>(cnt, bsum);
    k_scanblocks<<<1, 512, 0, stream>>>(bsum, bexcl);
    k_offsets   <<<NBLK, 256, 0, stream>>>(cnt, bexcl, off, pos,
                                           use_split ? offcnt : nullptr, dinv);
    k_build     <<<(N_EDGES + 255) / 256, 256, 0, stream>>>(row, col, pos, dinv, edge);

    if (use_split) {
        k_gather<0><<<(N_NODES + 3) / 4, 256, 0, stream>>>(x, ea, offcnt,
                                                           edge, dinv, act);
        k_gemm     <<<N_NODES / 32, 128, 0, stream>>>(act, Wn1, We1, b1, h1);
        k_gather<1><<<(N_NODES + 3) / 4, 256, 0, stream>>>(h1, nullptr, offcnt,
                                                           edge, dinv, act);
        k_gemm_final<<<N_NODES / 32, 128, 0, stream>>>(
            act, Wn2, We2, b2, x, Wo, bo, lng, lnb, (float*)d_out);
    } else {
        k_layer<<<N_NODES / 16, 256, 0, stream>>>(x, ea, nullptr, Ea,
                                                  off, cnt, edge, dinv,
                                                  Wn1, We1, b1, h1, 0);
        k_layer<<<N_NODES / 16, 256, 0, stream>>>(h1, nullptr, Ea, nullptr,
                                                  off, cnt, edge, dinv,
                                                  Wn2, We2, b2, h2, 1);
        k_final<<<N_NODES / 16, 256, 0, stream>>>(h2, x, Wo, bo, lng, lnb, (float*)d_out);
    }
}

// Round 7
// 806.219 us; speedup vs baseline: 1.1706x; 1.0301x over previous
//
#include <hip/hip_runtime.h>
#include <math.h>

#define N_NODES 100000
#define N_EDGES 800000
#define NBLK 391  // ceil(N_NODES/256)

__device__ __forceinline__ float gelu_f(float v) {
    return 0.5f * v * (1.0f + erff(v * 0.70710678f)); // exact gelu
}

// ----------------------------------------------------------- CSR construction
__global__ void k_count(const int* __restrict__ col, int* __restrict__ cnt) {
    int e = blockIdx.x * 256 + threadIdx.x;
    if (e < N_EDGES) {
        unsigned c = (unsigned)col[e];
        if (c < N_NODES) atomicAdd(&cnt[c], 1);
    }
}

__global__ void k_blocksum(const int* __restrict__ cnt, int* __restrict__ bsum) {
    __shared__ int sc[256];
    int t = threadIdx.x, i = blockIdx.x * 256 + t;
    sc[t] = (i < N_NODES) ? cnt[i] : 0;
    __syncthreads();
    for (int o = 128; o; o >>= 1) {
        if (t < o) sc[t] += sc[t + o];
        __syncthreads();
    }
    if (t == 0) bsum[blockIdx.x] = sc[0];
}

// one-block parallel scan over the 391 block sums
__global__ void k_scanblocks(const int* __restrict__ bsum, int* __restrict__ bexcl) {
    __shared__ int s[512];
    int t = threadIdx.x;
    s[t] = (t < NBLK) ? bsum[t] : 0;
    __syncthreads();
    for (int o = 1; o < 512; o <<= 1) {
        int v = (t >= o) ? s[t - o] : 0;
        __syncthreads();
        s[t] += v;
        __syncthreads();
    }
    if (t < NBLK) bexcl[t] = t ? s[t - 1] : 0;
}

// offsets + pos + packed {off,cnt} + dinv (k_dinv folded in)
__global__ void k_offsets(const int* __restrict__ cnt, const int* __restrict__ bexcl,
                          int* __restrict__ off, int* __restrict__ pos,
                          int2* __restrict__ offcnt, float* __restrict__ dinv) {
    __shared__ int sc[256];
    int t = threadIdx.x, i = blockIdx.x * 256 + t;
    int v = (i < N_NODES) ? cnt[i] : 0;
    sc[t] = v;
    __syncthreads();
    for (int o = 1; o < 256; o <<= 1) {
        int tv = (t >= o) ? sc[t - o] : 0;
        __syncthreads();
        sc[t] += tv;
        __syncthreads();
    }
    if (i < N_NODES) {
        int s = bexcl[blockIdx.x] + (sc[t] - v);
        off[i] = s;
        pos[i] = s;
        if (offcnt) offcnt[i] = make_int2(s, v);
        dinv[i] = rsqrtf((float)(v + 1)); // +1 self-loop
    }
}

// builds CSR with PACKED 16B records: ONE global_store_dwordx4 per edge
__global__ void k_build(const int* __restrict__ row, const int* __restrict__ col,
                        int* __restrict__ pos, const float* __restrict__ dinv,
                        int4* __restrict__ edge) {
    int e = blockIdx.x * 256 + threadIdx.x;
    if (e < N_EDGES) {
        unsigned r = (unsigned)row[e], c = (unsigned)col[e];
        if (r < N_NODES && c < N_NODES) {
            int slot = atomicAdd(&pos[c], 1);
            edge[slot] = make_int4((int)r, e, __float_as_int(dinv[r]), 0);
        }
    }
}

// -------------------------------------------------- latency-optimized gather
// One wave per destination node. Flat-16: bulk scalar loads of packed edge
// records, then all vector gathers issued in one round. Pad lanes (i >= d)
// get v=0 and are redirected to entry 0's row (L1 hit, zero extra HBM).
// Writes the finished activation row:
//   act[c][0:128]   = dinv[c]*aggX + dinv[c]^2 * X[c]
//   act[c][128:192] = dinv[c]*aggEA   (mode 0 only; layer-invariant)
template<int MODE>
__global__ __launch_bounds__(256) void k_gather(
    const float* __restrict__ X, const float* __restrict__ EAraw,
    const int2* __restrict__ offcnt, const int4* __restrict__ edge,
    const float* __restrict__ dinv, float* __restrict__ act)
{
    int w = threadIdx.x >> 6, l = threadIdx.x & 63;
    int c = blockIdx.x * 4 + w;
    if (c >= N_NODES) return;
    int2 oc = offcnt[c];
    int beg = __builtin_amdgcn_readfirstlane(oc.x);
    int d   = __builtin_amdgcn_readfirstlane(oc.y);
    const float2* X2 = (const float2*)X;

    float2 xc = X2[(size_t)c * 64 + l];   // self row: issue early, overlaps gathers
    float dv = dinv[c];

    // ---- bulk wave-uniform metadata loads (one contiguous 256B record block)
    int sU[16]; float vU[16]; int eU[16];
    #pragma unroll
    for (int i = 0; i < 16; i++) {
        int4 E = edge[beg + i];
        sU[i] = E.x;
        eU[i] = E.y;
        vU[i] = __int_as_float(E.z);
    }
    int s0 = (d > 0) ? sU[0] : 0;      // d==0 -> index 0 (valid row, v=0 anyway)
    int e0 = (d > 0) ? eU[0] : 0;
    #pragma unroll
    for (int i = 0; i < 16; i++) {
        if (i >= d) {                   // wave-uniform scalar select per i
            vU[i] = 0.f;
            sU[i] = s0;
            eU[i] = e0;
        }
    }

    // ---- issue all gathers before any accumulation
    float2 xv[16];
    #pragma unroll
    for (int i = 0; i < 16; i++) xv[i] = X2[(size_t)sU[i] * 64 + l];
    float evv[16];
    if (MODE == 0) {
        #pragma unroll
        for (int i = 0; i < 16; i++) evv[i] = EAraw[(size_t)eU[i] * 64 + l];
    }

    // sequential accumulation (keeps absmax low)
    float a0 = 0.f, a1 = 0.f, ae = 0.f;
    #pragma unroll
    for (int i = 0; i < 16; i++) {
        a0 += vU[i] * xv[i].x;
        a1 += vU[i] * xv[i].y;
        if (MODE == 0) ae += vU[i] * evv[i];
    }

    // ---- rare tail (P(d>16) ~ 0.4% for Poisson(8))
    for (int j = 16; j < d; j++) {
        int4 E = edge[beg + j];
        float v = __int_as_float(E.z);
        float2 x = X2[(size_t)E.x * 64 + l];
        a0 += v * x.x;
        a1 += v * x.y;
        if (MODE == 0) ae += v * EAraw[(size_t)E.y * 64 + l];
    }

    float dv2 = dv * dv;
    float* arow = act + (size_t)c * 192;
    ((float2*)arow)[l] = make_float2(dv * a0 + dv2 * xc.x, dv * a1 + dv2 * xc.y);
    if (MODE == 0) arow[128 + l] = dv * ae;
}

// -------------------------------------------------- LDS-lean GEMM (layer 1)
// h1[c] = gelu( act[c][0:192] @ [Wn;We] + bias )
// HALF-WAVE SPLIT: lane = (rowHalf h, colQuad q). Each lane computes 8 rows x
// 4 cols (32 accs, same as before) but a ds_read_b128 now feeds 16 FMAs
// instead of 8 -> ds_read instrs per k-group drop 16 -> 8. Round-6 PMC showed
// the GEMMs are LDS-issue-bound (~12 cyc x 1280 reads/wave ~= measured dur),
// so halving reads is the lever. The two half-waves read two row addresses per
// instr (2-way same-bank = free, m136). Weights load as float4 (4 contiguous
// cols); the cross-half duplicate hits L1.
__global__ __launch_bounds__(128, 3) void k_gemm(
    const float* __restrict__ act,
    const float* __restrict__ Wn, const float* __restrict__ We,
    const float* __restrict__ bias, float* __restrict__ out)
{
    __shared__ float sact[32][192];
    int t = threadIdx.x;
    int w = t >> 6, l = t & 63;
    int h = l >> 5, q = l & 31;

    size_t base = (size_t)blockIdx.x * (32 * 192);
    #pragma unroll
    for (int i = 0; i < 12; i++) {
        *(float4*)&sact[0][(i * 128 + t) * 4] =
            *(const float4*)(act + base + (size_t)(i * 128 + t) * 4);
    }
    __syncthreads();

    int rbase = w * 16 + h * 8;             // LDS row base for this lane
    int row0  = blockIdx.x * 32 + rbase;    // global row base
    float4 acc[8] = {};

    const float4* Wn4 = (const float4*)Wn;
    const float4* We4 = (const float4*)We;

    float4 n0 = Wn4[q], n1 = Wn4[32 + q], n2 = Wn4[64 + q], n3 = Wn4[96 + q];
    for (int k = 0; k < 192; k += 4) {
        float4 w0 = n0, w1 = n1, w2 = n2, w3 = n3;
        int kn = k + 4;
        if (kn < 192) {
            const float4* Wp = (kn < 128) ? (Wn4 + (size_t)kn * 32)
                                          : (We4 + (size_t)(kn - 128) * 32);
            n0 = Wp[q]; n1 = Wp[32 + q]; n2 = Wp[64 + q]; n3 = Wp[96 + q];
        }
        #pragma unroll
        for (int r = 0; r < 8; r++) {
            float4 a = *(const float4*)&sact[rbase + r][k];
            acc[r].x += a.x * w0.x + a.y * w1.x + a.z * w2.x + a.w * w3.x;
            acc[r].y += a.x * w0.y + a.y * w1.y + a.z * w2.y + a.w * w3.y;
            acc[r].z += a.x * w0.z + a.y * w1.z + a.z * w2.z + a.w * w3.z;
            acc[r].w += a.x * w0.w + a.y * w1.w + a.z * w2.w + a.w * w3.w;
        }
    }

    float4 bb = ((const float4*)bias)[q];
    #pragma unroll
    for (int r = 0; r < 8; r++) {
        float4 v;
        v.x = gelu_f(acc[r].x + bb.x);
        v.y = gelu_f(acc[r].y + bb.y);
        v.z = gelu_f(acc[r].z + bb.z);
        v.w = gelu_f(acc[r].w + bb.w);
        ((float4*)out)[(size_t)(row0 + r) * 32 + q] = v;
    }
}

// ------------------------- layer-2 GEMM + residual + LayerNorm, fully fused.
// Same half-wave split. Weight prefetch chain runs Wn -> We -> Wo across phase
// boundaries. h2 stays in the wave's own LDS rows (DS in-order within a wave).
// LN row-reduce: a row lives in one 32-lane half -> 5 shuffles (xor 16..1).
__global__ __launch_bounds__(128, 3) void k_gemm_final(
    const float* __restrict__ act,
    const float* __restrict__ Wn, const float* __restrict__ We,
    const float* __restrict__ bias, const float* __restrict__ x,
    const float* __restrict__ Wo, const float* __restrict__ bo,
    const float* __restrict__ g, const float* __restrict__ lb,
    float* __restrict__ out)
{
    __shared__ float sact[32][192];
    int t = threadIdx.x;
    int w = t >> 6, l = t & 63;
    int h = l >> 5, q = l & 31;

    size_t base = (size_t)blockIdx.x * (32 * 192);
    #pragma unroll
    for (int i = 0; i < 12; i++) {
        *(float4*)&sact[0][(i * 128 + t) * 4] =
            *(const float4*)(act + base + (size_t)(i * 128 + t) * 4);
    }
    __syncthreads();

    int rbase = w * 16 + h * 8;
    int row0  = blockIdx.x * 32 + rbase;
    float4 acc[8] = {};

    const float4* Wn4 = (const float4*)Wn;
    const float4* We4 = (const float4*)We;
    const float4* Wo4 = (const float4*)Wo;

    // ---- phase 2: h2 = gelu(act @ [Wn;We] + b)
    float4 n0 = Wn4[q], n1 = Wn4[32 + q], n2 = Wn4[64 + q], n3 = Wn4[96 + q];
    for (int k = 0; k < 192; k += 4) {
        float4 w0 = n0, w1 = n1, w2 = n2, w3 = n3;
        int kn = k + 4;
        const float4* Wp = (kn < 128) ? (Wn4 + (size_t)kn * 32)
                         : (kn < 192) ? (We4 + (size_t)(kn - 128) * 32)
                                      : Wo4;          // kn==192: prefetch Wo k=0..3
        n0 = Wp[q]; n1 = Wp[32 + q]; n2 = Wp[64 + q]; n3 = Wp[96 + q];
        #pragma unroll
        for (int r = 0; r < 8; r++) {
            float4 a = *(const float4*)&sact[rbase + r][k];
            acc[r].x += a.x * w0.x + a.y * w1.x + a.z * w2.x + a.w * w3.x;
            acc[r].y += a.x * w0.y + a.y * w1.y + a.z * w2.y + a.w * w3.y;
            acc[r].z += a.x * w0.z + a.y * w1.z + a.z * w2.z + a.w * w3.z;
            acc[r].w += a.x * w0.w + a.y * w1.w + a.z * w2.w + a.w * w3.w;
        }
    }

    // gelu -> h2 into the wave's OWN rows (Wo prefetch in flight meanwhile)
    float4 bb = ((const float4*)bias)[q];
    #pragma unroll
    for (int r = 0; r < 8; r++) {
        float4 v;
        v.x = gelu_f(acc[r].x + bb.x);
        v.y = gelu_f(acc[r].y + bb.y);
        v.z = gelu_f(acc[r].z + bb.z);
        v.w = gelu_f(acc[r].w + bb.w);
        *(float4*)&sact[rbase + r][4 * q] = v;
        acc[r] = make_float4(0.f, 0.f, 0.f, 0.f);   // reuse acc for phase 3
    }

    // ---- phase 3: out = LayerNorm(h2 @ Wo + bo + x)
    for (int k = 0; k < 128; k += 4) {
        float4 w0 = n0, w1 = n1, w2 = n2, w3 = n3;
        int kn = k + 4;
        if (kn < 128) {
            const float4* Wp = Wo4 + (size_t)kn * 32;
            n0 = Wp[q]; n1 = Wp[32 + q]; n2 = Wp[64 + q]; n3 = Wp[96 + q];
        }
        #pragma unroll
        for (int r = 0; r < 8; r++) {
            float4 a = *(const float4*)&sact[rbase + r][k];
            acc[r].x += a.x * w0.x + a.y * w1.x + a.z * w2.x + a.w * w3.x;
            acc[r].y += a.x * w0.y + a.y * w1.y + a.z * w2.y + a.w * w3.y;
            acc[r].z += a.x * w0.z + a.y * w1.z + a.z * w2.z + a.w * w3.z;
            acc[r].w += a.x * w0.w + a.y * w1.w + a.z * w2.w + a.w * w3.w;
        }
    }

    float4 bov = ((const float4*)bo)[q];
    float4 gv  = ((const float4*)g)[q];
    float4 lbv = ((const float4*)lb)[q];
    const float4* X4 = (const float4*)x;

    #pragma unroll
    for (int r = 0; r < 8; r++) {
        int c = row0 + r;
        float4 xv = X4[(size_t)c * 32 + q];
        float v0 = acc[r].x + bov.x + xv.x;
        float v1 = acc[r].y + bov.y + xv.y;
        float v2 = acc[r].z + bov.z + xv.z;
        float v3 = acc[r].w + bov.w + xv.w;
        float s = (v0 + v1) + (v2 + v3);
        #pragma unroll
        for (int o = 16; o; o >>= 1) s += __shfl_xor(s, o, 64);  // within 32-lane half
        float mu = s * (1.0f / 128.0f);
        float d0 = v0 - mu, d1 = v1 - mu, d2 = v2 - mu, d3 = v3 - mu;
        float sq = (d0 * d0 + d1 * d1) + (d2 * d2 + d3 * d3);
        #pragma unroll
        for (int o = 16; o; o >>= 1) sq += __shfl_xor(sq, o, 64);
        float rs = rsqrtf(sq * (1.0f / 128.0f) + 1e-5f);
        float4 ov;
        ov.x = d0 * rs * gv.x + lbv.x;
        ov.y = d1 * rs * gv.y + lbv.y;
        ov.z = d2 * rs * gv.z + lbv.z;
        ov.w = d3 * rs * gv.w + lbv.w;
        ((float4*)out)[(size_t)c * 32 + q] = ov;
    }
}

// --------------------- fused fallback (proven path, small workspace)
__global__ __launch_bounds__(256) void k_layer(
    const float* __restrict__ X, const float* __restrict__ EAraw,
    const float* __restrict__ EaIn, float* __restrict__ EaOut,
    const int* __restrict__ off, const int* __restrict__ cnt,
    const int4* __restrict__ edge, const float* __restrict__ dinv,
    const float* __restrict__ Wn, const float* __restrict__ We,
    const float* __restrict__ bias, float* __restrict__ out, int mode)
{
    __shared__ float act[4][4][192];
    int w = threadIdx.x >> 6, l = threadIdx.x & 63;
    int row0 = blockIdx.x * 16 + w * 4;

    for (int r = 0; r < 4; r++) {
        int c = row0 + r;
        int beg = off[c];
        int d = cnt[c];
        float a0 = 0.f, a1 = 0.f, ae = 0.f;
        for (int j = 0; j < d; j++) {
            int4 E = edge[beg + j];
            unsigned s = (unsigned)E.x;
            if (s >= N_NODES) continue;
            float sv = __int_as_float(E.z);
            float2 xv = ((const float2*)X)[s * 64 + l];
            a0 += sv * xv.x;
            a1 += sv * xv.y;
            if (mode == 0) {
                unsigned e = (unsigned)E.y;
                if (e < N_EDGES) ae += sv * EAraw[e * 64 + l];
            }
        }
        float dv = dinv[c], dv2 = dv * dv;
        float2 xc = ((const float2*)X)[c * 64 + l];
        act[w][r][2 * l]     = dv * a0 + dv2 * xc.x;
        act[w][r][2 * l + 1] = dv * a1 + dv2 * xc.y;
        if (mode == 0) {
            act[w][r][128 + l] = dv * ae;
            EaOut[c * 64 + l] = ae;
        } else {
            act[w][r][128 + l] = dv * EaIn[c * 64 + l];
        }
    }
    __syncthreads();

    float acc[4][2] = {};
    for (int k = 0; k < 128; k++) {
        float2 wv = ((const float2*)Wn)[k * 64 + l];
        #pragma unroll
        for (int r = 0; r < 4; r++) {
            float a = act[w][r][k];
            acc[r][0] += a * wv.x;
            acc[r][1] += a * wv.y;
        }
    }
    for (int k = 0; k < 64; k++) {
        float2 wv = ((const float2*)We)[k * 64 + l];
        #pragma unroll
        for (int r = 0; r < 4; r++) {
            float a = act[w][r][128 + k];
            acc[r][0] += a * wv.x;
            acc[r][1] += a * wv.y;
        }
    }

    float2 bb = ((const float2*)bias)[l];
    for (int r = 0; r < 4; r++) {
        float v0 = acc[r][0] + bb.x;
        float v1 = acc[r][1] + bb.y;
        ((float2*)out)[(row0 + r) * 64 + l] = make_float2(gelu_f(v0), gelu_f(v1));
    }
}

// ------------------------------------ final (fallback path only)
__global__ __launch_bounds__(256) void k_final(
    const float* __restrict__ h2, const float* __restrict__ x,
    const float* __restrict__ Wo, const float* __restrict__ bo,
    const float* __restrict__ g, const float* __restrict__ lb,
    float* __restrict__ out)
{
    __shared__ float lds[4][4][128];
    int w = threadIdx.x >> 6, l = threadIdx.x & 63;
    int row0 = blockIdx.x * 16 + w * 4;

    for (int r = 0; r < 4; r++) {
        int c = row0 + r;
        float2 hv = ((const float2*)h2)[(size_t)c * 64 + l];
        lds[w][r][2 * l]     = hv.x;
        lds[w][r][2 * l + 1] = hv.y;
    }
    __syncthreads();

    float acc[4][2] = {};
    const float2* Wo2 = (const float2*)Wo;
    for (int k = 0; k < 128; k += 4) {
        float2 w0 = Wo2[(k + 0) * 64 + l];
        float2 w1 = Wo2[(k + 1) * 64 + l];
        float2 w2 = Wo2[(k + 2) * 64 + l];
        float2 w3 = Wo2[(k + 3) * 64 + l];
        #pragma unroll
        for (int r = 0; r < 4; r++) {
            float4 a = *(const float4*)&lds[w][r][k];
            acc[r][0] += a.x * w0.x + a.y * w1.x + a.z * w2.x + a.w * w3.x;
            acc[r][1] += a.x * w0.y + a.y * w1.y + a.z * w2.y + a.w * w3.y;
        }
    }

    float2 bov = ((const float2*)bo)[l];
    float2 gv  = ((const float2*)g)[l];
    float2 lbv = ((const float2*)lb)[l];

    for (int r = 0; r < 4; r++) {
        int c = row0 + r;
        float2 xv = ((const float2*)x)[(size_t)c * 64 + l];
        float v0 = acc[r][0] + bov.x + xv.x;
        float v1 = acc[r][1] + bov.y + xv.y;
        float s = v0 + v1;
        #pragma unroll
        for (int o = 32; o; o >>= 1) s += __shfl_xor(s, o, 64);
        float mu = s * (1.0f / 128.0f);
        float d0 = v0 - mu, d1 = v1 - mu;
        float sq = d0 * d0 + d1 * d1;
        #pragma unroll
        for (int o = 32; o; o >>= 1) sq += __shfl_xor(sq, o, 64);
        float rs = rsqrtf(sq * (1.0f / 128.0f) + 1e-5f);
        float2 ov;
        ov.x = d0 * rs * gv.x + lbv.x;
        ov.y = d1 * rs * gv.y + lbv.y;
        ((float2*)out)[(size_t)c * 64 + l] = ov;
    }
}

extern "C" void kernel_launch(void* const* d_in, const int* in_sizes, int n_in,
                              void* d_out, int out_size, void* d_ws, size_t ws_size,
                              hipStream_t stream)
{
    const float* x   = (const float*)d_in[0];
    const int*   ei  = (const int*)d_in[1];
    const float* ea  = (const float*)d_in[2];
    // d_in[3..6] (W_qkv, b_qkv, W_ek, b_ek) are dead code in the reference.
    const float* Wn1 = (const float*)d_in[7];
    const float* We1 = (const float*)d_in[8];
    const float* b1  = (const float*)d_in[9];
    const float* Wn2 = (const float*)d_in[10];
    const float* We2 = (const float*)d_in[11];
    const float* b2  = (const float*)d_in[12];
    const float* Wo  = (const float*)d_in[13];
    const float* bo  = (const float*)d_in[14];
    const float* lng = (const float*)d_in[15];
    const float* lnb = (const float*)d_in[16];
    const int* row = ei;
    const int* col = ei + N_EDGES;

    char* ws = (char*)d_ws;
    size_t off_b = 0;
    auto alloc = [&](size_t bytes) {
        void* p = ws + off_b;
        off_b += (bytes + 255) & ~(size_t)255;
        return p;
    };
    // ---- common workspace: CSR (packed 16B edge records, padded +16) + h1
    int*   cnt   = (int*)  alloc((size_t)N_NODES * 4);
    int*   off   = (int*)  alloc((size_t)N_NODES * 4);
    int*   pos   = (int*)  alloc((size_t)N_NODES * 4);
    int*   bsum  = (int*)  alloc((size_t)NBLK * 4);
    int*   bexcl = (int*)  alloc((size_t)NBLK * 4);
    float* dinv  = (float*)alloc((size_t)N_NODES * 4);
    int4*  edge  = (int4*) alloc((size_t)(N_EDGES + 16) * 16);
    float* h1    = (float*)alloc((size_t)N_NODES * 128 * 4);
    size_t common_end = off_b;

    // ---- split-path extras: offcnt + act[N][192]
    int2*  offcnt = (int2*) alloc((size_t)N_NODES * 8);
    float* act    = (float*)alloc((size_t)N_NODES * 192 * 4);
    size_t split_end = off_b;

    // ---- fused-path extras overlap the split-path region (paths exclusive)
    float* Ea = (float*)(ws + common_end);
    size_t fused_end = common_end + (((size_t)N_NODES * 64 * 4 + 255) & ~(size_t)255);

    bool use_split = (split_end <= ws_size);
    if (!use_split && fused_end > ws_size) return; // finite-wrong signature, diagnosable

    float* h2 = (float*)d_out;    // fallback path stages h2 in d_out

    hipMemsetAsync(cnt, 0, (size_t)N_NODES * 4, stream);

    k_count     <<<(N_EDGES + 255) / 256, 256, 0, stream>>>(col, cnt);
    k_blocksum  <<<NBLK, 256, 0, stream>>>(cnt, bsum);
    k_scanblocks<<<1, 512, 0, stream>>>(bsum, bexcl);
    k_offsets   <<<NBLK, 256, 0, stream>>>(cnt, bexcl, off, pos,
                                           use_split ? offcnt : nullptr, dinv);
    k_build     <<<(N_EDGES + 255) / 256, 256, 0, stream>>>(row, col, pos, dinv, edge);

    if (use_split) {
        k_gather<0><<<(N_NODES + 3) / 4, 256, 0, stream>>>(x, ea, offcnt,
                                                           edge, dinv, act);
        k_gemm     <<<N_NODES / 32, 128, 0, stream>>>(act, Wn1, We1, b1, h1);
        k_gather<1><<<(N_NODES + 3) / 4, 256, 0, stream>>>(h1, nullptr, offcnt,
                                                           edge, dinv, act);
        k_gemm_final<<<N_NODES / 32, 128, 0, stream>>>(
            act, Wn2, We2, b2, x, Wo, bo, lng, lnb, (float*)d_out);
    } else {
        k_layer<<<N_NODES / 16, 256, 0, stream>>>(x, ea, nullptr, Ea,
                                                  off, cnt, edge, dinv,
                                                  Wn1, We1, b1, h1, 0);
        k_layer<<<N_NODES / 16, 256, 0, stream>>>(h1, nullptr, Ea, nullptr,
                                                  off, cnt, edge, dinv,
                                                  Wn2, We2, b2, h2, 1);
        k_final<<<N_NODES / 16, 256, 0, stream>>>(h2, x, Wo, bo, lng, lnb, (float*)d_out);
    }
}

// Round 8
// 805.346 us; speedup vs baseline: 1.1718x; 1.0011x over previous
//
#include <hip/hip_runtime.h>
#include <math.h>

#define N_NODES 100000
#define N_EDGES 800000
#define NBLK 391  // ceil(N_NODES/256)

__device__ __forceinline__ float gelu_f(float v) {
    return 0.5f * v * (1.0f + erff(v * 0.70710678f)); // exact gelu
}

// ----------------------------------------------------------- CSR construction
__global__ void k_count(const int* __restrict__ col, int* __restrict__ cnt) {
    int e = blockIdx.x * 256 + threadIdx.x;
    if (e < N_EDGES) {
        unsigned c = (unsigned)col[e];
        if (c < N_NODES) atomicAdd(&cnt[c], 1);
    }
}

__global__ void k_blocksum(const int* __restrict__ cnt, int* __restrict__ bsum) {
    __shared__ int sc[256];
    int t = threadIdx.x, i = blockIdx.x * 256 + t;
    sc[t] = (i < N_NODES) ? cnt[i] : 0;
    __syncthreads();
    for (int o = 128; o; o >>= 1) {
        if (t < o) sc[t] += sc[t + o];
        __syncthreads();
    }
    if (t == 0) bsum[blockIdx.x] = sc[0];
}

// one-block parallel scan over the 391 block sums
__global__ void k_scanblocks(const int* __restrict__ bsum, int* __restrict__ bexcl) {
    __shared__ int s[512];
    int t = threadIdx.x;
    s[t] = (t < NBLK) ? bsum[t] : 0;
    __syncthreads();
    for (int o = 1; o < 512; o <<= 1) {
        int v = (t >= o) ? s[t - o] : 0;
        __syncthreads();
        s[t] += v;
        __syncthreads();
    }
    if (t < NBLK) bexcl[t] = t ? s[t - 1] : 0;
}

// offsets + pos + packed {off,cnt} + dinv (k_dinv folded in)
__global__ void k_offsets(const int* __restrict__ cnt, const int* __restrict__ bexcl,
                          int* __restrict__ off, int* __restrict__ pos,
                          int2* __restrict__ offcnt, float* __restrict__ dinv) {
    __shared__ int sc[256];
    int t = threadIdx.x, i = blockIdx.x * 256 + t;
    int v = (i < N_NODES) ? cnt[i] : 0;
    sc[t] = v;
    __syncthreads();
    for (int o = 1; o < 256; o <<= 1) {
        int tv = (t >= o) ? sc[t - o] : 0;
        __syncthreads();
        sc[t] += tv;
        __syncthreads();
    }
    if (i < N_NODES) {
        int s = bexcl[blockIdx.x] + (sc[t] - v);
        off[i] = s;
        pos[i] = s;
        if (offcnt) offcnt[i] = make_int2(s, v);
        dinv[i] = rsqrtf((float)(v + 1)); // +1 self-loop
    }
}

// builds CSR with PACKED 16B records: ONE global_store_dwordx4 per edge
__global__ void k_build(const int* __restrict__ row, const int* __restrict__ col,
                        int* __restrict__ pos, const float* __restrict__ dinv,
                        int4* __restrict__ edge) {
    int e = blockIdx.x * 256 + threadIdx.x;
    if (e < N_EDGES) {
        unsigned r = (unsigned)row[e], c = (unsigned)col[e];
        if (r < N_NODES && c < N_NODES) {
            int slot = atomicAdd(&pos[c], 1);
            edge[slot] = make_int4((int)r, e, __float_as_int(dinv[r]), 0);
        }
    }
}

// ===================== fused gather + GEMM (+final for MODE 1) =============
// Block = 256 threads = 4 waves = 32 output rows. Phase 1: wave w flat-16-
// gathers its 8 rows (nodes blockIdx*32 + w*8 + j) directly into LDS -- the
// act[N][192] HBM round-trip of the split pipeline is gone (~230 MB saved
// across both layers). The layer-invariant edge aggregate dv*ae is persisted
// once via EaS (25.6 MB). Phase 2: half-split GEMM (lane = (h,q): 4 rows x
// 4 cols, 16:1 FMA:ds_read) identical math order to rounds 5-7.
// Rationale: gather is memory-bound (16% VALUBusy), GEMM compute-bound
// (8% HBM) -- fused, resident blocks at different phases overlap the two.
// MODE 0: X=x, writes h1.  MODE 1: X=h1, + Wo/residual/LayerNorm -> out.
template<int MODE>
__global__ __launch_bounds__(256, 2) void k_fused(
    const float* __restrict__ X, const float* __restrict__ EAraw,
    const int2* __restrict__ offcnt, const int4* __restrict__ edge,
    const float* __restrict__ dinv, float* __restrict__ EaS,
    const float* __restrict__ Wn, const float* __restrict__ We,
    const float* __restrict__ bias,
    const float* __restrict__ xres, const float* __restrict__ Wo,
    const float* __restrict__ bo, const float* __restrict__ g,
    const float* __restrict__ lb,
    float* __restrict__ out)
{
    __shared__ float sact[32][192];
    int t = threadIdx.x;
    int w = t >> 6, l = t & 63;

    // ---------------- phase 1: gather 8 rows per wave into LDS
    const float2* X2 = (const float2*)X;
    for (int j = 0; j < 8; j++) {
        int c = blockIdx.x * 32 + w * 8 + j;
        int2 oc = offcnt[c];
        int beg = __builtin_amdgcn_readfirstlane(oc.x);
        int d   = __builtin_amdgcn_readfirstlane(oc.y);

        float2 xc = X2[(size_t)c * 64 + l];   // self row, overlaps gathers
        float dv = dinv[c];

        int sU[16]; float vU[16]; int eU[16];
        #pragma unroll
        for (int i = 0; i < 16; i++) {
            int4 E = edge[beg + i];
            sU[i] = E.x;
            eU[i] = E.y;
            vU[i] = __int_as_float(E.z);
        }
        int s0 = (d > 0) ? sU[0] : 0;
        int e0 = (d > 0) ? eU[0] : 0;
        #pragma unroll
        for (int i = 0; i < 16; i++) {
            if (i >= d) {                 // pad -> entry 0's row (L1 hit, v=0)
                vU[i] = 0.f;
                sU[i] = s0;
                eU[i] = e0;
            }
        }

        float2 xv[16];
        #pragma unroll
        for (int i = 0; i < 16; i++) xv[i] = X2[(size_t)sU[i] * 64 + l];
        float evv[16];
        if (MODE == 0) {
            #pragma unroll
            for (int i = 0; i < 16; i++) evv[i] = EAraw[(size_t)eU[i] * 64 + l];
        }

        float a0 = 0.f, a1 = 0.f, ae = 0.f;
        #pragma unroll
        for (int i = 0; i < 16; i++) {
            a0 += vU[i] * xv[i].x;
            a1 += vU[i] * xv[i].y;
            if (MODE == 0) ae += vU[i] * evv[i];
        }
        for (int jj = 16; jj < d; jj++) {          // rare tail
            int4 E = edge[beg + jj];
            float v = __int_as_float(E.z);
            float2 xx = X2[(size_t)E.x * 64 + l];
            a0 += v * xx.x;
            a1 += v * xx.y;
            if (MODE == 0) ae += v * EAraw[(size_t)E.y * 64 + l];
        }

        float dv2 = dv * dv;
        int rr = w * 8 + j;
        sact[rr][2 * l]     = dv * a0 + dv2 * xc.x;
        sact[rr][2 * l + 1] = dv * a1 + dv2 * xc.y;
        if (MODE == 0) {
            float s = dv * ae;
            sact[rr][128 + l] = s;
            EaS[(size_t)c * 64 + l] = s;           // persist for layer 2
        } else {
            sact[rr][128 + l] = EaS[(size_t)c * 64 + l];
        }
    }
    __syncthreads();

    // ---------------- phase 2: GEMM. lane=(h,q): rows rbase..rbase+3, cols 4q..4q+3
    int h = l >> 5, q = l & 31;
    int rbase = w * 8 + h * 4;
    int row0  = blockIdx.x * 32 + rbase;
    float4 acc[4] = {};

    const float4* Wn4 = (const float4*)Wn;
    const float4* We4 = (const float4*)We;
    const float4* Wo4 = (const float4*)Wo;

    float4 n0 = Wn4[q], n1 = Wn4[32 + q], n2 = Wn4[64 + q], n3 = Wn4[96 + q];
    for (int k = 0; k < 192; k += 4) {
        float4 w0 = n0, w1 = n1, w2 = n2, w3 = n3;
        int kn = k + 4;
        const float4* Wp = (kn < 128) ? (Wn4 + (size_t)kn * 32)
                         : (kn < 192) ? (We4 + (size_t)(kn - 128) * 32)
                         : (MODE == 1 ? Wo4 : Wn4);   // M1: prefetch Wo k=0..3
        n0 = Wp[q]; n1 = Wp[32 + q]; n2 = Wp[64 + q]; n3 = Wp[96 + q];
        #pragma unroll
        for (int r = 0; r < 4; r++) {
            float4 a = *(const float4*)&sact[rbase + r][k];
            acc[r].x += a.x * w0.x + a.y * w1.x + a.z * w2.x + a.w * w3.x;
            acc[r].y += a.x * w0.y + a.y * w1.y + a.z * w2.y + a.w * w3.y;
            acc[r].z += a.x * w0.z + a.y * w1.z + a.z * w2.z + a.w * w3.z;
            acc[r].w += a.x * w0.w + a.y * w1.w + a.z * w2.w + a.w * w3.w;
        }
    }

    float4 bb = ((const float4*)bias)[q];

    if (MODE == 0) {
        #pragma unroll
        for (int r = 0; r < 4; r++) {
            float4 v;
            v.x = gelu_f(acc[r].x + bb.x);
            v.y = gelu_f(acc[r].y + bb.y);
            v.z = gelu_f(acc[r].z + bb.z);
            v.w = gelu_f(acc[r].w + bb.w);
            ((float4*)out)[(size_t)(row0 + r) * 32 + q] = v;
        }
        return;
    }

    // ---- MODE 1: gelu -> back into the wave's OWN rows (in-wave DS ordering)
    #pragma unroll
    for (int r = 0; r < 4; r++) {
        float4 v;
        v.x = gelu_f(acc[r].x + bb.x);
        v.y = gelu_f(acc[r].y + bb.y);
        v.z = gelu_f(acc[r].z + bb.z);
        v.w = gelu_f(acc[r].w + bb.w);
        *(float4*)&sact[rbase + r][4 * q] = v;
        acc[r] = make_float4(0.f, 0.f, 0.f, 0.f);
    }

    // ---- phase 3: out = LayerNorm(h2 @ Wo + bo + x)
    for (int k = 0; k < 128; k += 4) {
        float4 w0 = n0, w1 = n1, w2 = n2, w3 = n3;
        int kn = k + 4;
        if (kn < 128) {
            const float4* Wp = Wo4 + (size_t)kn * 32;
            n0 = Wp[q]; n1 = Wp[32 + q]; n2 = Wp[64 + q]; n3 = Wp[96 + q];
        }
        #pragma unroll
        for (int r = 0; r < 4; r++) {
            float4 a = *(const float4*)&sact[rbase + r][k];
            acc[r].x += a.x * w0.x + a.y * w1.x + a.z * w2.x + a.w * w3.x;
            acc[r].y += a.x * w0.y + a.y * w1.y + a.z * w2.y + a.w * w3.y;
            acc[r].z += a.x * w0.z + a.y * w1.z + a.z * w2.z + a.w * w3.z;
            acc[r].w += a.x * w0.w + a.y * w1.w + a.z * w2.w + a.w * w3.w;
        }
    }

    float4 bov = ((const float4*)bo)[q];
    float4 gv  = ((const float4*)g)[q];
    float4 lbv = ((const float4*)lb)[q];
    const float4* X4 = (const float4*)xres;

    #pragma unroll
    for (int r = 0; r < 4; r++) {
        int c = row0 + r;
        float4 xv = X4[(size_t)c * 32 + q];
        float v0 = acc[r].x + bov.x + xv.x;
        float v1 = acc[r].y + bov.y + xv.y;
        float v2 = acc[r].z + bov.z + xv.z;
        float v3 = acc[r].w + bov.w + xv.w;
        float s = (v0 + v1) + (v2 + v3);
        #pragma unroll
        for (int o = 16; o; o >>= 1) s += __shfl_xor(s, o, 64);  // within half
        float mu = s * (1.0f / 128.0f);
        float d0 = v0 - mu, d1 = v1 - mu, d2 = v2 - mu, d3 = v3 - mu;
        float sq = (d0 * d0 + d1 * d1) + (d2 * d2 + d3 * d3);
        #pragma unroll
        for (int o = 16; o; o >>= 1) sq += __shfl_xor(sq, o, 64);
        float rs = rsqrtf(sq * (1.0f / 128.0f) + 1e-5f);
        float4 ov;
        ov.x = d0 * rs * gv.x + lbv.x;
        ov.y = d1 * rs * gv.y + lbv.y;
        ov.z = d2 * rs * gv.z + lbv.z;
        ov.w = d3 * rs * gv.w + lbv.w;
        ((float4*)out)[(size_t)c * 32 + q] = ov;
    }
}

// --------------------- fused fallback (proven path, small workspace)
__global__ __launch_bounds__(256) void k_layer(
    const float* __restrict__ X, const float* __restrict__ EAraw,
    const float* __restrict__ EaIn, float* __restrict__ EaOut,
    const int* __restrict__ off, const int* __restrict__ cnt,
    const int4* __restrict__ edge, const float* __restrict__ dinv,
    const float* __restrict__ Wn, const float* __restrict__ We,
    const float* __restrict__ bias, float* __restrict__ out, int mode)
{
    __shared__ float act[4][4][192];
    int w = threadIdx.x >> 6, l = threadIdx.x & 63;
    int row0 = blockIdx.x * 16 + w * 4;

    for (int r = 0; r < 4; r++) {
        int c = row0 + r;
        int beg = off[c];
        int d = cnt[c];
        float a0 = 0.f, a1 = 0.f, ae = 0.f;
        for (int j = 0; j < d; j++) {
            int4 E = edge[beg + j];
            unsigned s = (unsigned)E.x;
            if (s >= N_NODES) continue;
            float sv = __int_as_float(E.z);
            float2 xv = ((const float2*)X)[s * 64 + l];
            a0 += sv * xv.x;
            a1 += sv * xv.y;
            if (mode == 0) {
                unsigned e = (unsigned)E.y;
                if (e < N_EDGES) ae += sv * EAraw[e * 64 + l];
            }
        }
        float dv = dinv[c], dv2 = dv * dv;
        float2 xc = ((const float2*)X)[c * 64 + l];
        act[w][r][2 * l]     = dv * a0 + dv2 * xc.x;
        act[w][r][2 * l + 1] = dv * a1 + dv2 * xc.y;
        if (mode == 0) {
            act[w][r][128 + l] = dv * ae;
            EaOut[c * 64 + l] = ae;
        } else {
            act[w][r][128 + l] = dv * EaIn[c * 64 + l];
        }
    }
    __syncthreads();

    float acc[4][2] = {};
    for (int k = 0; k < 128; k++) {
        float2 wv = ((const float2*)Wn)[k * 64 + l];
        #pragma unroll
        for (int r = 0; r < 4; r++) {
            float a = act[w][r][k];
            acc[r][0] += a * wv.x;
            acc[r][1] += a * wv.y;
        }
    }
    for (int k = 0; k < 64; k++) {
        float2 wv = ((const float2*)We)[k * 64 + l];
        #pragma unroll
        for (int r = 0; r < 4; r++) {
            float a = act[w][r][128 + k];
            acc[r][0] += a * wv.x;
            acc[r][1] += a * wv.y;
        }
    }

    float2 bb = ((const float2*)bias)[l];
    for (int r = 0; r < 4; r++) {
        float v0 = acc[r][0] + bb.x;
        float v1 = acc[r][1] + bb.y;
        ((float2*)out)[(row0 + r) * 64 + l] = make_float2(gelu_f(v0), gelu_f(v1));
    }
}

// ------------------------------------ final (fallback path only)
__global__ __launch_bounds__(256) void k_final(
    const float* __restrict__ h2, const float* __restrict__ x,
    const float* __restrict__ Wo, const float* __restrict__ bo,
    const float* __restrict__ g, const float* __restrict__ lb,
    float* __restrict__ out)
{
    __shared__ float lds[4][4][128];
    int w = threadIdx.x >> 6, l = threadIdx.x & 63;
    int row0 = blockIdx.x * 16 + w * 4;

    for (int r = 0; r < 4; r++) {
        int c = row0 + r;
        float2 hv = ((const float2*)h2)[(size_t)c * 64 + l];
        lds[w][r][2 * l]     = hv.x;
        lds[w][r][2 * l + 1] = hv.y;
    }
    __syncthreads();

    float acc[4][2] = {};
    const float2* Wo2 = (const float2*)Wo;
    for (int k = 0; k < 128; k += 4) {
        float2 w0 = Wo2[(k + 0) * 64 + l];
        float2 w1 = Wo2[(k + 1) * 64 + l];
        float2 w2 = Wo2[(k + 2) * 64 + l];
        float2 w3 = Wo2[(k + 3) * 64 + l];
        #pragma unroll
        for (int r = 0; r < 4; r++) {
            float4 a = *(const float4*)&lds[w][r][k];
            acc[r][0] += a.x * w0.x + a.y * w1.x + a.z * w2.x + a.w * w3.x;
            acc[r][1] += a.x * w0.y + a.y * w1.y + a.z * w2.y + a.w * w3.y;
        }
    }

    float2 bov = ((const float2*)bo)[l];
    float2 gv  = ((const float2*)g)[l];
    float2 lbv = ((const float2*)lb)[l];

    for (int r = 0; r < 4; r++) {
        int c = row0 + r;
        float2 xv = ((const float2*)x)[(size_t)c * 64 + l];
        float v0 = acc[r][0] + bov.x + xv.x;
        float v1 = acc[r][1] + bov.y + xv.y;
        float s = v0 + v1;
        #pragma unroll
        for (int o = 32; o; o >>= 1) s += __shfl_xor(s, o, 64);
        float mu = s * (1.0f / 128.0f);
        float d0 = v0 - mu, d1 = v1 - mu;
        float sq = d0 * d0 + d1 * d1;
        #pragma unroll
        for (int o = 32; o; o >>= 1) sq += __shfl_xor(sq, o, 64);
        float rs = rsqrtf(sq * (1.0f / 128.0f) + 1e-5f);
        float2 ov;
        ov.x = d0 * rs * gv.x + lbv.x;
        ov.y = d1 * rs * gv.y + lbv.y;
        ((float2*)out)[(size_t)c * 64 + l] = ov;
    }
}

extern "C" void kernel_launch(void* const* d_in, const int* in_sizes, int n_in,
                              void* d_out, int out_size, void* d_ws, size_t ws_size,
                              hipStream_t stream)
{
    const float* x   = (const float*)d_in[0];
    const int*   ei  = (const int*)d_in[1];
    const float* ea  = (const float*)d_in[2];
    // d_in[3..6] (W_qkv, b_qkv, W_ek, b_ek) are dead code in the reference.
    const float* Wn1 = (const float*)d_in[7];
    const float* We1 = (const float*)d_in[8];
    const float* b1  = (const float*)d_in[9];
    const float* Wn2 = (const float*)d_in[10];
    const float* We2 = (const float*)d_in[11];
    const float* b2  = (const float*)d_in[12];
    const float* Wo  = (const float*)d_in[13];
    const float* bo  = (const float*)d_in[14];
    const float* lng = (const float*)d_in[15];
    const float* lnb = (const float*)d_in[16];
    const int* row = ei;
    const int* col = ei + N_EDGES;

    char* ws = (char*)d_ws;
    size_t off_b = 0;
    auto alloc = [&](size_t bytes) {
        void* p = ws + off_b;
        off_b += (bytes + 255) & ~(size_t)255;
        return p;
    };
    // ---- common workspace: CSR (packed 16B edge records, padded +16) + h1
    int*   cnt   = (int*)  alloc((size_t)N_NODES * 4);
    int*   off   = (int*)  alloc((size_t)N_NODES * 4);
    int*   pos   = (int*)  alloc((size_t)N_NODES * 4);
    int*   bsum  = (int*)  alloc((size_t)NBLK * 4);
    int*   bexcl = (int*)  alloc((size_t)NBLK * 4);
    float* dinv  = (float*)alloc((size_t)N_NODES * 4);
    int4*  edge  = (int4*) alloc((size_t)(N_EDGES + 16) * 16);
    float* h1    = (float*)alloc((size_t)N_NODES * 128 * 4);
    size_t common_end = off_b;

    // ---- split-path extras: offcnt + EaS (layer-invariant edge aggregate)
    int2*  offcnt = (int2*) alloc((size_t)N_NODES * 8);
    float* EaS    = (float*)alloc((size_t)N_NODES * 64 * 4);
    size_t split_end = off_b;

    // ---- fallback-path extras overlap the split-path region (exclusive)
    float* Ea = (float*)(ws + common_end);
    size_t fused_end = common_end + (((size_t)N_NODES * 64 * 4 + 255) & ~(size_t)255);

    bool use_split = (split_end <= ws_size);
    if (!use_split && fused_end > ws_size) return; // finite-wrong signature, diagnosable

    float* h2 = (float*)d_out;    // fallback path stages h2 in d_out

    hipMemsetAsync(cnt, 0, (size_t)N_NODES * 4, stream);

    k_count     <<<(N_EDGES + 255) / 256, 256, 0, stream>>>(col, cnt);
    k_blocksum  <<<NBLK, 256, 0, stream>>>(cnt, bsum);
    k_scanblocks<<<1, 512, 0, stream>>>(bsum, bexcl);
    k_offsets   <<<NBLK, 256, 0, stream>>>(cnt, bexcl, off, pos,
                                           use_split ? offcnt : nullptr, dinv);
    k_build     <<<(N_EDGES + 255) / 256, 256, 0, stream>>>(row, col, pos, dinv, edge);

    if (use_split) {
        k_fused<0><<<N_NODES / 32, 256, 0, stream>>>(
            x, ea, offcnt, edge, dinv, EaS,
            Wn1, We1, b1, nullptr, nullptr, nullptr, nullptr, nullptr, h1);
        k_fused<1><<<N_NODES / 32, 256, 0, stream>>>(
            h1, nullptr, offcnt, edge, dinv, EaS,
            Wn2, We2, b2, x, Wo, bo, lng, lnb, (float*)d_out);
    } else {
        k_layer<<<N_NODES / 16, 256, 0, stream>>>(x, ea, nullptr, Ea,
                                                  off, cnt, edge, dinv,
                                                  Wn1, We1, b1, h1, 0);
        k_layer<<<N_NODES / 16, 256, 0, stream>>>(h1, nullptr, Ea, nullptr,
                                                  off, cnt, edge, dinv,
                                                  Wn2, We2, b2, h2, 1);
        k_final<<<N_NODES / 16, 256, 0, stream>>>(h2, x, Wo, bo, lng, lnb, (float*)d_out);
    }
}